// Round 6
// baseline (297.303 us; speedup 1.0000x reference)
//
#include <hip/hip_runtime.h>
#include <math.h>

#define T_SEQ 28
#define D_IN  28
#define H     128
#define NTHR  512
#define NTHR0 1024

typedef short bf16x8 __attribute__((ext_vector_type(8)));   // 8 bf16 = 4 VGPR (A/B frag)
typedef short bf16x2 __attribute__((ext_vector_type(2)));
typedef float f32x4  __attribute__((ext_vector_type(4)));   // C/D frag
typedef unsigned u32x4 __attribute__((ext_vector_type(4)));

// ws layout: W0 frags [ut][f0:20][lane][8] | W1 frags [ut][f1:32][lane][8] | biases fp32 | h0seq
#define NW0E (8*20*512)                     // 81920 ushorts
#define NW1E (8*32*512)                     // 131072 ushorts
#define BIAS_OFF_BYTES ((NW0E + NW1E) * 2)  // 425984 B
#define SEQ_OFF_BYTES  (BIAS_OFF_BYTES + 4096)
#define SEQ_ELEMS      ((size_t)512 * T_SEQ * 2048)          // bf16 elements
#define NEED_WS        (SEQ_OFF_BYTES + SEQ_ELEMS * 2)       // ~59.2 MB

__device__ __forceinline__ unsigned short f2bf(float f) {
    unsigned u = __float_as_uint(f);
    u += 0x7fffu + ((u >> 16) & 1u);        // round-to-nearest-even
    return (unsigned short)(u >> 16);
}
__device__ __forceinline__ float bf2f(unsigned short h) {
    return __uint_as_float(((unsigned)h) << 16);
}
__device__ __forceinline__ unsigned pkbf2(float a, float b) {
#if __has_builtin(__builtin_amdgcn_cvt_pk_bf16_f32)
    bf16x2 r = __builtin_amdgcn_cvt_pk_bf16_f32(a, b);
    return __builtin_bit_cast(unsigned, r);
#else
    return (unsigned)f2bf(a) | ((unsigned)f2bf(b) << 16);
#endif
}
// Fast activations: v_rcp_f32 (1 ulp) instead of the IEEE div sequence.
__device__ __forceinline__ float frcp(float x)   { return __builtin_amdgcn_rcpf(x); }
__device__ __forceinline__ float sigm(float x)   { return frcp(1.0f + __expf(-x)); }
__device__ __forceinline__ float tanhf_(float x) { return 1.0f - 2.0f * frcp(1.0f + __expf(2.0f * x)); }

// Opaque-def pin: blocks rematerialization of the one-time weight loads.
__device__ __forceinline__ void pin(bf16x8& v) { asm volatile("" : "+v"(v)); }

// LDS-only barrier: cross-wave dependence inside the t-loop is LDS only.
#define LDS_BARRIER() asm volatile("s_waitcnt lgkmcnt(0)\ns_barrier" ::: "memory")

#define MFMA(acc, a, b) acc = __builtin_amdgcn_mfma_f32_16x16x32_bf16(a, b, acc, 0, 0, 0)

// One LSTM elementwise h-value (10 trans). Compile-time v via macro expansion.
#define ELEMV(accX, csX, v, dst) { \
    float ig_ = sigm(accX[0][v]); \
    float fg_ = sigm(accX[1][v]); \
    float gg_ = tanhf_(accX[2][v]); \
    float og_ = sigm(accX[3][v]); \
    float c_  = fg_ * csX[v] + ig_ * gg_; \
    csX[v] = c_; \
    dst = og_ * tanhf_(c_); }

// Pack 2 h-values and write into frag-order XOR layout (rows r0, r0+1).
#define WRPAIR(hdst, r0, h0, h1) { \
    unsigned u_ = pkbf2(h0, h1); \
    int b0_ = quad*4 + (r0); \
    (hdst)[b0_*128     + ((jc ^ b0_)*8)     + jl] = (unsigned short)u_; \
    (hdst)[(b0_+1)*128 + ((jc ^ (b0_+1))*8) + jl] = (unsigned short)(u_ >> 16); }

// Pack weights into exact B-fragment order: B[k][n], n = lane&15, k = (lane>>4)*8 + j.
__global__ void prep(const float* __restrict__ Wih0, const float* __restrict__ Whh0,
                     const float* __restrict__ bih0, const float* __restrict__ bhh0,
                     const float* __restrict__ Wih1, const float* __restrict__ Whh1,
                     const float* __restrict__ bih1, const float* __restrict__ bhh1,
                     unsigned short* __restrict__ W, float* __restrict__ bias) {
    int i = blockIdx.x * 256 + threadIdx.x;
    if (i < NW0E) {
        int ut = i / (20*512), r = i % (20*512);
        int f = r >> 9, e = r & 511;
        int lane = e >> 3, j = e & 7;
        int lrow = lane & 15, quad = lane >> 4;
        float v;
        if (f < 4) {                        // x-part: K=28 padded to 32
            int gt = f, k = quad*8 + j;
            int g = gt*128 + ut*16 + lrow;
            v = (k < D_IN) ? Wih0[g*D_IN + k] : 0.0f;
        } else {                            // h0-part: 4 K-steps
            int ks = (f-4) >> 2, gt = (f-4) & 3;
            int g = gt*128 + ut*16 + lrow;
            v = Whh0[g*H + ks*32 + quad*8 + j];
        }
        W[i] = f2bf(v);
    } else if (i < NW0E + NW1E) {
        int i2 = i - NW0E;
        int ut = i2 / (32*512), r = i2 % (32*512);
        int f = r >> 9, e = r & 511;
        int lane = e >> 3, j = e & 7;
        int lrow = lane & 15, quad = lane >> 4;
        int ks = f >> 2, gt = f & 3;        // ks 0..3 = Wih1, 4..7 = Whh1
        int g = gt*128 + ut*16 + lrow;
        float v = (ks < 4) ? Wih1[g*H + ks*32 + quad*8 + j]
                           : Whh1[g*H + (ks-4)*32 + quad*8 + j];
        W[i] = f2bf(v);
    } else if (i < NW0E + NW1E + 1024) {
        int g = i - NW0E - NW1E;
        if (g < 512) bias[g] = bih0[g] + bhh0[g];
        else         bias[g] = bih1[g-512] + bhh1[g-512];
    }
}

// ================= Phase kernels ==========
// h0seq layout: [bt16:512][t:28][cc:4][lane:64][el:8] bf16 — exact A-frag order.
//
// R6: 16-WAVE BLOCK FOR l0. R2-R5 established: (a) blocks/CU is pinned at 1
// by HW regardless of LDS/VGPR; (b) per-t cost ~6700cyc is invariant to
// barrier count / interleave => ~half the time is dependency stall that
// 2 waves/SIMD cannot hide. A 1024-thread block is scheduled as a UNIT ->
// 16 waves/CU = 4 waves/SIMD guaranteed (needs VGPR<=128). Waves 0-7 own
// tile A, waves 8-15 own tile B; per wave = 1 tile x 4gt = 20 MFMA + 4
// ELEMV per t (half of R5's per-wave work, spread over 2x waves).

// Layer 0: grid 256, BT=32, NTHR0=1024.
__global__ __attribute__((amdgpu_waves_per_eu(4, 4))) __launch_bounds__(NTHR0)
void lstm_l0(
    const float* __restrict__ x, const unsigned short* __restrict__ W,
    const float* __restrict__ bias, unsigned short* __restrict__ h0seq)
{
    __shared__ __align__(16) unsigned short hA[2][16*128];   // 8 KB (double buffer)
    __shared__ __align__(16) unsigned short hB[2][16*128];   // 8 KB

    const int tid = threadIdx.x, lane = tid & 63;
    const int w   = tid >> 6;            // wave 0..15
    const int g   = w >> 3;              // tile group: 0 = A, 1 = B
    const int ut  = w & 7;               // column-slice (same weights for both groups)
    const int lrow = lane & 15, quad = lane >> 4;
    const int blk = blockIdx.x;          // 0..255
    const int bbase = blk * 32;

    for (int i = tid; i < 16*128; i += NTHR0) {
        hA[0][i] = 0; hA[1][i] = 0; hB[0][i] = 0; hB[1][i] = 0;
    }

    const unsigned short* w0p = W + ut*10240 + lane*8;
    bf16x8 wxf[4];
#pragma unroll
    for (int f = 0; f < 4; ++f)  { wxf[f] = *(const bf16x8*)(w0p + f*512);     pin(wxf[f]); }
    bf16x8 wh[16];
#pragma unroll
    for (int f = 0; f < 16; ++f) { wh[f] = *(const bf16x8*)(w0p + (4+f)*512); pin(wh[f]); }

    float cs[4] = {0.f,0.f,0.f,0.f};
    float bv[4];
#pragma unroll
    for (int gt = 0; gt < 4; ++gt) bv[gt] = bias[gt*128 + ut*16 + lrow];

    const float* xr = x + (size_t)(bbase + g*16 + lrow) * (T_SEQ*D_IN) + quad*8;
    const int jc = (ut*16 + lrow) >> 3, jl = (ut*16 + lrow) & 7;

    // store mapping: waves {0-3} store tile A, waves {8-11} store tile B
    const bool sstore = ((w & 4) == 0);
    const int scc = w & 3;               // cc 0..3 within tile
    const int sq2 = lane >> 4, sb = lane & 15;
    const int schunk = (scc*4 + sq2) ^ sb;
    unsigned short* sdst = h0seq + (size_t)(2*blk + g)*(T_SEQ*2048) + scc*512 + lane*8;

#define L0_LDH(hrd_, ks_) (*(const bf16x8*)&(hrd_)[lrow*128 + ((((ks_)*4 + quad) ^ lrow)*8)])
#define L0_KS(accX, ah_, ks_) { \
        MFMA(accX[0], ah_, wh[(ks_)*4+0]); \
        MFMA(accX[1], ah_, wh[(ks_)*4+1]); \
        MFMA(accX[2], ah_, wh[(ks_)*4+2]); \
        MFMA(accX[3], ah_, wh[(ks_)*4+3]); }

    // preload x(t=0) for this wave's tile
    float4 lo = *(const float4*)xr;
    float4 hi = make_float4(0.f,0.f,0.f,0.f);
    if (quad < 3) hi = *(const float4*)(xr+4);

    __syncthreads();

#pragma unroll 1
    for (int t = 0; t < T_SEQ; ++t) {
        const int rdi = (t+1) & 1, wri = t & 1;     // read h(t-1), write h(t)
        const unsigned short* hrd = g ? hB[rdi] : hA[rdi];
        unsigned short* hwr = g ? hB[wri] : hA[wri];

        // store h(t-1) to h0seq (rd buffer, RO this segment)
        if (t > 0 && sstore) {
            bf16x8 hv = *(const bf16x8*)&hrd[sb*128 + schunk*8];
            *(bf16x8*)(sdst + (size_t)(t-1)*2048) = hv;
        }

        // hoist the 4 A-frag ds_reads
        bf16x8 ah0 = L0_LDH(hrd, 0), ah1 = L0_LDH(hrd, 1);
        bf16x8 ah2 = L0_LDH(hrd, 2), ah3 = L0_LDH(hrd, 3);

        u32x4 ua;
        ua[0]=pkbf2(lo.x,lo.y); ua[1]=pkbf2(lo.z,lo.w);
        ua[2]=pkbf2(hi.x,hi.y); ua[3]=pkbf2(hi.z,hi.w);
        bf16x8 ax = __builtin_bit_cast(bf16x8, ua);

        f32x4 acc[4];
#pragma unroll
        for (int gt = 0; gt < 4; ++gt) { f32x4 s = {bv[gt],bv[gt],bv[gt],bv[gt]}; acc[gt] = s; }
#pragma unroll
        for (int gt = 0; gt < 4; ++gt) MFMA(acc[gt], ax, wxf[gt]);
        L0_KS(acc, ah0, 0);
        L0_KS(acc, ah1, 1);
        L0_KS(acc, ah2, 2);
        L0_KS(acc, ah3, 3);

        // prefetch x(t+1) — latency hidden under elem + cross-wave overlap
        if (t + 1 < T_SEQ) {
            const float* p = xr + (t+1)*D_IN;
            lo = *(const float4*)p;
            hi = make_float4(0.f,0.f,0.f,0.f);
            if (quad < 3) hi = *(const float4*)(p+4);
        }

        // elementwise -> wr buffer
        {
            float h0, h1;
            ELEMV(acc, cs, 0, h0); ELEMV(acc, cs, 1, h1); WRPAIR(hwr, 0, h0, h1);
            ELEMV(acc, cs, 2, h0); ELEMV(acc, cs, 3, h1); WRPAIR(hwr, 2, h0, h1);
        }

        LDS_BARRIER();
    }

    // final store h(T-1): buf[1] (27&1==1); last barrier already executed
    if (sstore) {
        const unsigned short* hrd = g ? hB[1] : hA[1];
        bf16x8 hv = *(const bf16x8*)&hrd[sb*128 + schunk*8];
        *(bf16x8*)(sdst + (size_t)(T_SEQ-1)*2048) = hv;
    }
#undef L0_LDH
#undef L0_KS
}

// Layer 1 + FC + log_softmax: grid 256, lockstep 2-tile, one barrier/t.
// (unchanged from R5 — 128 pinned weight VGPRs preclude the 4-wave budget;
// will be redesigned only if l0's 16-wave experiment validates the lever.)
__global__ __attribute__((amdgpu_waves_per_eu(2, 2))) __launch_bounds__(NTHR)
void lstm_l1(
    const unsigned short* __restrict__ h0seq, const unsigned short* __restrict__ W,
    const float* __restrict__ bias, const float* __restrict__ Wfc,
    const float* __restrict__ bfc, float* __restrict__ out)
{
    __shared__ __align__(16) unsigned short hA[2][16*128];   // 8 KB
    __shared__ __align__(16) unsigned short hB[2][16*128];   // 8 KB
    __shared__ float lg[320];

    const int tid = threadIdx.x, lane = tid & 63, ut = tid >> 6;
    const int lrow = lane & 15, quad = lane >> 4;
    const int blk = blockIdx.x;
    const int bbase = blk * 32;

    for (int i = tid; i < 16*128; i += NTHR) {
        hA[0][i] = 0; hA[1][i] = 0; hB[0][i] = 0; hB[1][i] = 0;
    }

    const unsigned short* w1p = W + NW0E + ut*16384 + lane*8;
    bf16x8 w1a[16], w1b[16];                 // Wih1 (ks0..3), Whh1 (ks4..7)
#pragma unroll
    for (int f = 0; f < 16; ++f) { w1a[f] = *(const bf16x8*)(w1p + f*512);        pin(w1a[f]); }
#pragma unroll
    for (int f = 0; f < 16; ++f) { w1b[f] = *(const bf16x8*)(w1p + (16+f)*512);   pin(w1b[f]); }

    float cA[4] = {0.f,0.f,0.f,0.f}, cB[4] = {0.f,0.f,0.f,0.f};
    float bv1[4];
#pragma unroll
    for (int gt = 0; gt < 4; ++gt) bv1[gt] = bias[512 + gt*128 + ut*16 + lrow];

    const unsigned short* sqA = h0seq + (size_t)(2*blk)   * (T_SEQ*2048) + lane*8;
    const unsigned short* sqB = h0seq + (size_t)(2*blk+1) * (T_SEQ*2048) + lane*8;
    const int jc = (ut*16 + lrow) >> 3, jl = (ut*16 + lrow) & 7;

#define L1_LDH(hrd_, ks_) (*(const bf16x8*)&(hrd_)[lrow*128 + ((((ks_)*4 + quad) ^ lrow)*8)])
#define L1_XS(accX, ga_, cc_) { \
        MFMA(accX[0], ga_[cc_], w1a[(cc_)*4+0]); \
        MFMA(accX[1], ga_[cc_], w1a[(cc_)*4+1]); \
        MFMA(accX[2], ga_[cc_], w1a[(cc_)*4+2]); \
        MFMA(accX[3], ga_[cc_], w1a[(cc_)*4+3]); }
#define L1_HS(accX, ah_, ks_) { \
        MFMA(accX[0], ah_, w1b[(ks_)*4+0]); \
        MFMA(accX[1], ah_, w1b[(ks_)*4+1]); \
        MFMA(accX[2], ah_, w1b[(ks_)*4+2]); \
        MFMA(accX[3], ah_, w1b[(ks_)*4+3]); }

    // preload ga(t=0) for both tiles
    bf16x8 gaA[4], gaB[4];
#pragma unroll
    for (int cc = 0; cc < 4; ++cc) gaA[cc] = *(const bf16x8*)(sqA + cc*512);
#pragma unroll
    for (int cc = 0; cc < 4; ++cc) gaB[cc] = *(const bf16x8*)(sqB + cc*512);

    __syncthreads();

#pragma unroll 1
    for (int t = 0; t < T_SEQ; ++t) {
        const int rdi = (t+1) & 1, wri = t & 1;
        const unsigned short* hArd = hA[rdi];
        const unsigned short* hBrd = hB[rdi];

        // hoist all 8 A-frag ds_reads
        bf16x8 ah0 = L1_LDH(hArd, 0), ah1 = L1_LDH(hArd, 1);
        bf16x8 ah2 = L1_LDH(hArd, 2), ah3 = L1_LDH(hArd, 3);
        bf16x8 bh0 = L1_LDH(hBrd, 0), bh1 = L1_LDH(hBrd, 1);
        bf16x8 bh2 = L1_LDH(hBrd, 2), bh3 = L1_LDH(hBrd, 3);

        f32x4 accA[4], accB[4];
#pragma unroll
        for (int gt = 0; gt < 4; ++gt) {
            f32x4 s = {bv1[gt],bv1[gt],bv1[gt],bv1[gt]};
            accA[gt] = s; accB[gt] = s;
        }
        // x-part (register operands) first
        L1_XS(accA, gaA, 0); L1_XS(accB, gaB, 0);
        L1_XS(accA, gaA, 1); L1_XS(accB, gaB, 1);
        L1_XS(accA, gaA, 2); L1_XS(accB, gaB, 2);
        L1_XS(accA, gaA, 3); L1_XS(accB, gaB, 3);
        // h-part
        L1_HS(accA, ah0, 0); L1_HS(accB, bh0, 0);
        L1_HS(accA, ah1, 1); L1_HS(accB, bh1, 1);
        L1_HS(accA, ah2, 2); L1_HS(accB, bh2, 2);
        L1_HS(accA, ah3, 3); L1_HS(accB, bh3, 3);

        // prefetch ga(t+1)
        if (t + 1 < T_SEQ) {
#pragma unroll
            for (int cc = 0; cc < 4; ++cc) gaA[cc] = *(const bf16x8*)(sqA + (t+1)*2048 + cc*512);
#pragma unroll
            for (int cc = 0; cc < 4; ++cc) gaB[cc] = *(const bf16x8*)(sqB + (t+1)*2048 + cc*512);
        }

        // elementwise both tiles -> wr buffers
        {
            float h0, h1;
            ELEMV(accA, cA, 0, h0); ELEMV(accA, cA, 1, h1); WRPAIR(hA[wri], 0, h0, h1);
            ELEMV(accA, cA, 2, h0); ELEMV(accA, cA, 3, h1); WRPAIR(hA[wri], 2, h0, h1);
            ELEMV(accB, cB, 0, h0); ELEMV(accB, cB, 1, h1); WRPAIR(hB[wri], 0, h0, h1);
            ELEMV(accB, cB, 2, h0); ELEMV(accB, cB, 3, h1); WRPAIR(hB[wri], 2, h0, h1);
        }

        LDS_BARRIER();
    }

    // FC + log_softmax. h1(T-1) in buf[1] (T-1=27). Last barrier already done.
    if (tid < 320) {
        int c = tid >> 5, b = tid & 31;
        int bl = b & 15;
        const unsigned short* hs = (b < 16) ? hA[1] : hB[1];
        float s = bfc[c];
        const float* wr = Wfc + c*H;
#pragma unroll
        for (int j8 = 0; j8 < 16; ++j8) {        // vectorized LDS read (bf16x8)
            bf16x8 hv = *(const bf16x8*)&hs[bl*128 + ((j8 ^ bl)*8)];
#pragma unroll
            for (int k = 0; k < 8; ++k)
                s = fmaf(wr[j8*8 + k], bf2f((unsigned short)hv[k]), s);
        }
        lg[c*32 + b] = s;
    }
    __syncthreads();
    if (tid < 32) {
        int b = tid;
        float m = -1e30f;
#pragma unroll
        for (int c = 0; c < 10; ++c) m = fmaxf(m, lg[c*32 + b]);
        float ssum = 0.f;
#pragma unroll
        for (int c = 0; c < 10; ++c) ssum += __expf(lg[c*32 + b] - m);
        float ls = m + __logf(ssum);
        float* op = out + (size_t)(bbase + b) * 10;
#pragma unroll
        for (int c = 0; c < 10; ++c) op[c] = lg[c*32 + b] - ls;
    }
#undef L1_LDH
#undef L1_XS
#undef L1_HS
}

// ================= Monolithic fallback =====================
__global__ __attribute__((amdgpu_waves_per_eu(2, 2))) __launch_bounds__(NTHR)
void lstm_mfma(
    const float* __restrict__ x, const unsigned short* __restrict__ W,
    const float* __restrict__ bias,
    const float* __restrict__ Wfc, const float* __restrict__ bfc,
    float* __restrict__ out)
{
    __shared__ __align__(16) unsigned short h0s[2][32*128];
    __shared__ __align__(16) unsigned short h1s[32*128];
    __shared__ __align__(16) unsigned short wl[8*16*512];

    const int tid  = threadIdx.x;
    const int lane = tid & 63;
    const int ut   = tid >> 6;
    const int lrow = lane & 15;
    const int quad = lane >> 4;
    const int bbase = blockIdx.x * 32;

    for (int i = tid; i < 32*128; i += NTHR) { h0s[0][i] = 0; h0s[1][i] = 0; h1s[i] = 0; }
#pragma unroll
    for (int it = 0; it < 16; ++it) {
        int i = it * (NTHR*8) + tid*8;
        int utw = i >> 13, r = i & 8191;
        *(bf16x8*)&wl[i] = *(const bf16x8*)&W[NW0E + utw*16384 + 8192 + r];
    }
    const unsigned short* w0p = W + ut*(20*512) + lane*8;
    const unsigned short* w1p = W + NW0E + ut*(32*512) + lane*8;
    bf16x8 w0x[4], w0h[16], w1h[16];
#pragma unroll
    for (int f = 0; f < 4; ++f)  w0x[f] = *(const bf16x8*)(w0p + f*512);
#pragma unroll
    for (int f = 0; f < 16; ++f) w0h[f] = *(const bf16x8*)(w0p + (4+f)*512);
#pragma unroll
    for (int f = 0; f < 16; ++f) w1h[f] = *(const bf16x8*)(w1p + f*512);

    float c0[2][4], c1[2][4];
#pragma unroll
    for (int m = 0; m < 2; ++m)
#pragma unroll
        for (int r = 0; r < 4; ++r) { c0[m][r] = 0.f; c1[m][r] = 0.f; }
    float bv0[4], bv1[4];
#pragma unroll
    for (int gt = 0; gt < 4; ++gt) {
        bv0[gt] = bias[gt*128 + ut*16 + lrow];
        bv1[gt] = bias[512 + gt*128 + ut*16 + lrow];
    }
    const float* xr0 = x + (size_t)(bbase + lrow)      * (T_SEQ*D_IN) + quad*8;
    const float* xr1 = x + (size_t)(bbase + 16 + lrow) * (T_SEQ*D_IN) + quad*8;
    const int jc = (ut*16 + lrow) >> 3;
    const int jl = (ut*16 + lrow) & 7;
    __syncthreads();

    auto step = [&](const unsigned short* __restrict__ h0rd,
                    unsigned short* __restrict__ h0wr, int t) {
        f32x4 acc[2][4];
#pragma unroll
        for (int gt = 0; gt < 4; ++gt) {
            f32x4 s = {bv0[gt], bv0[gt], bv0[gt], bv0[gt]};
            acc[0][gt] = s; acc[1][gt] = s;
        }
        {
            const float* p0 = xr0 + t*D_IN;
            const float* p1 = xr1 + t*D_IN;
            float4 lo0 = *(const float4*)p0;
            float4 lo1 = *(const float4*)p1;
            float4 hi0 = make_float4(0,0,0,0), hi1 = make_float4(0,0,0,0);
            if (quad < 3) { hi0 = *(const float4*)(p0+4); hi1 = *(const float4*)(p1+4); }
            u32x4 ua0, ua1;
            ua0[0] = pkbf2(lo0.x, lo0.y); ua0[1] = pkbf2(lo0.z, lo0.w);
            ua0[2] = pkbf2(hi0.x, hi0.y); ua0[3] = pkbf2(hi0.z, hi0.w);
            ua1[0] = pkbf2(lo1.x, lo1.y); ua1[1] = pkbf2(lo1.z, lo1.w);
            ua1[2] = pkbf2(hi1.x, hi1.y); ua1[3] = pkbf2(hi1.z, hi1.w);
            bf16x8 a0 = __builtin_bit_cast(bf16x8, ua0);
            bf16x8 a1 = __builtin_bit_cast(bf16x8, ua1);
#pragma unroll
            for (int gt = 0; gt < 4; ++gt) {
                MFMA(acc[0][gt], a0, w0x[gt]);
                MFMA(acc[1][gt], a1, w0x[gt]);
            }
        }
#pragma unroll
        for (int ks = 0; ks < 4; ++ks) {
            int cc = ks*4 + quad;
            bf16x8 a0 = *(const bf16x8*)&h0rd[lrow*128      + ((cc ^ lrow)*8)];
            bf16x8 a1 = *(const bf16x8*)&h0rd[(16+lrow)*128 + ((cc ^ lrow)*8)];
#pragma unroll
            for (int gt = 0; gt < 4; ++gt) {
                MFMA(acc[0][gt], a0, w0h[ks*4+gt]);
                MFMA(acc[1][gt], a1, w0h[ks*4+gt]);
            }
        }
#pragma unroll
        for (int m = 0; m < 2; ++m) {
#pragma unroll
            for (int r = 0; r < 4; r += 2) {
                float hv[2];
#pragma unroll
                for (int q = 0; q < 2; ++q) {
                    float ig = sigm(acc[m][0][r+q]);
                    float fg = sigm(acc[m][1][r+q]);
                    float gg = tanhf_(acc[m][2][r+q]);
                    float og = sigm(acc[m][3][r+q]);
                    float c  = fg * c0[m][r+q] + ig * gg;
                    c0[m][r+q] = c;
                    hv[q] = og * tanhf_(c);
                }
                unsigned u = pkbf2(hv[0], hv[1]);
                int b0 = m*16 + quad*4 + r;
                h0wr[b0*128     + ((jc ^ (b0&15))*8)     + jl] = (unsigned short)u;
                h0wr[(b0+1)*128 + ((jc ^ ((b0+1)&15))*8) + jl] = (unsigned short)(u >> 16);
            }
        }
        __syncthreads();
#pragma unroll
        for (int gt = 0; gt < 4; ++gt) {
            f32x4 s = {bv1[gt], bv1[gt], bv1[gt], bv1[gt]};
            acc[0][gt] = s; acc[1][gt] = s;
        }
#pragma unroll
        for (int ks = 0; ks < 4; ++ks) {
            int cc = ks*4 + quad;
            bf16x8 a0 = *(const bf16x8*)&h0wr[lrow*128      + ((cc ^ lrow)*8)];
            bf16x8 a1 = *(const bf16x8*)&h0wr[(16+lrow)*128 + ((cc ^ lrow)*8)];
#pragma unroll
            for (int gt = 0; gt < 4; ++gt) {
                MFMA(acc[0][gt], a0, w1h[ks*4+gt]);
                MFMA(acc[1][gt], a1, w1h[ks*4+gt]);
            }
        }
#pragma unroll
        for (int ks = 0; ks < 4; ++ks) {
            int cc = ks*4 + quad;
            bf16x8 a0 = *(const bf16x8*)&h1s[lrow*128      + ((cc ^ lrow)*8)];
            bf16x8 a1 = *(const bf16x8*)&h1s[(16+lrow)*128 + ((cc ^ lrow)*8)];
#pragma unroll
            for (int gt = 0; gt < 4; ++gt) {
                bf16x8 bf = *(const bf16x8*)&wl[ut*8192 + (ks*4+gt)*512 + lane*8];
                MFMA(acc[0][gt], a0, bf);
                MFMA(acc[1][gt], a1, bf);
            }
        }
        __syncthreads();
#pragma unroll
        for (int m = 0; m < 2; ++m) {
#pragma unroll
            for (int r = 0; r < 4; r += 2) {
                float hv[2];
#pragma unroll
                for (int q = 0; q < 2; ++q) {
                    float ig = sigm(acc[m][0][r+q]);
                    float fg = sigm(acc[m][1][r+q]);
                    float gg = tanhf_(acc[m][2][r+q]);
                    float og = sigm(acc[m][3][r+q]);
                    float c  = fg * c1[m][r+q] + ig * gg;
                    c1[m][r+q] = c;
                    hv[q] = og * tanhf_(c);
                }
                unsigned u = pkbf2(hv[0], hv[1]);
                int b0 = m*16 + quad*4 + r;
                h1s[b0*128     + ((jc ^ (b0&15))*8)     + jl] = (unsigned short)u;
                h1s[(b0+1)*128 + ((jc ^ ((b0+1)&15))*8) + jl] = (unsigned short)(u >> 16);
            }
        }
    };
#pragma unroll 1
    for (int t2 = 0; t2 < T_SEQ/2; ++t2) {
        step(h0s[0], h0s[1], 2*t2);
        step(h0s[1], h0s[0], 2*t2 + 1);
    }
    __syncthreads();
    float* lg = (float*)&h0s[0][0];
    if (tid < 320) {
        int c = tid >> 5, b = tid & 31;
        float s = bfc[c];
        const float* wr = Wfc + c*H;
#pragma unroll 4
        for (int j = 0; j < H; ++j)
            s = fmaf(wr[j], bf2f(h1s[b*128 + (((j>>3) ^ (b&15))*8) + (j&7)]), s);
        lg[c*32 + b] = s;
    }
    __syncthreads();
    if (tid < 32) {
        int b = tid;
        float m = -1e30f;
#pragma unroll
        for (int c = 0; c < 10; ++c) m = fmaxf(m, lg[c*32 + b]);
        float ssum = 0.f;
#pragma unroll
        for (int c = 0; c < 10; ++c) ssum += __expf(lg[c*32 + b] - m);
        float ls = m + __logf(ssum);
        float* op = out + (size_t)(bbase + b) * 10;
#pragma unroll
        for (int c = 0; c < 10; ++c) op[c] = lg[c*32 + b] - ls;
    }
}

extern "C" void kernel_launch(void* const* d_in, const int* in_sizes, int n_in,
                              void* d_out, int out_size, void* d_ws, size_t ws_size,
                              hipStream_t stream) {
    const float* x    = (const float*)d_in[0];
    const float* Wih0 = (const float*)d_in[1];
    const float* Whh0 = (const float*)d_in[2];
    const float* bih0 = (const float*)d_in[3];
    const float* bhh0 = (const float*)d_in[4];
    const float* Wih1 = (const float*)d_in[5];
    const float* Whh1 = (const float*)d_in[6];
    const float* bih1 = (const float*)d_in[7];
    const float* bhh1 = (const float*)d_in[8];
    const float* Wfc  = (const float*)d_in[9];
    const float* bfc  = (const float*)d_in[10];
    float* out = (float*)d_out;

    unsigned short* W = (unsigned short*)d_ws;
    float* bias = (float*)((char*)d_ws + BIAS_OFF_BYTES);

    const int n_prep = NW0E + NW1E + 1024;
    prep<<<(n_prep + 255) / 256, 256, 0, stream>>>(Wih0, Whh0, bih0, bhh0,
                                                   Wih1, Whh1, bih1, bhh1, W, bias);
    if (ws_size >= (size_t)NEED_WS) {
        unsigned short* h0seq = (unsigned short*)((char*)d_ws + SEQ_OFF_BYTES);
        lstm_l0<<<256, NTHR0, 0, stream>>>(x, W, bias, h0seq);
        lstm_l1<<<256, NTHR, 0, stream>>>(h0seq, W, bias, Wfc, bfc, out);
    } else {
        lstm_mfma<<<256, NTHR, 0, stream>>>(x, W, bias, Wfc, bfc, out);
    }
}

// Round 7
// 249.545 us; speedup vs baseline: 1.1914x; 1.1914x over previous
//
#include <hip/hip_runtime.h>
#include <math.h>

#define T_SEQ 28
#define D_IN  28
#define H     128
#define NTHR  512
#define NTHR0 1024

typedef short bf16x8 __attribute__((ext_vector_type(8)));   // 8 bf16 = 4 VGPR (A/B frag)
typedef short bf16x2 __attribute__((ext_vector_type(2)));
typedef float f32x4  __attribute__((ext_vector_type(4)));   // C/D frag
typedef unsigned u32x4 __attribute__((ext_vector_type(4)));

// ws layout: W0 frags [ut][f0:20][lane][8] | W1 frags [ut][f1:32][lane][8] | biases fp32 | h0seq
#define NW0E (8*20*512)                     // 81920 ushorts
#define NW1E (8*32*512)                     // 131072 ushorts
#define BIAS_OFF_BYTES ((NW0E + NW1E) * 2)  // 425984 B
#define SEQ_OFF_BYTES  (BIAS_OFF_BYTES + 4096)
#define SEQ_ELEMS      ((size_t)512 * T_SEQ * 2048)          // bf16 elements
#define NEED_WS        (SEQ_OFF_BYTES + SEQ_ELEMS * 2)       // ~59.2 MB

__device__ __forceinline__ unsigned short f2bf(float f) {
    unsigned u = __float_as_uint(f);
    u += 0x7fffu + ((u >> 16) & 1u);        // round-to-nearest-even
    return (unsigned short)(u >> 16);
}
__device__ __forceinline__ float bf2f(unsigned short h) {
    return __uint_as_float(((unsigned)h) << 16);
}
__device__ __forceinline__ unsigned pkbf2(float a, float b) {
#if __has_builtin(__builtin_amdgcn_cvt_pk_bf16_f32)
    bf16x2 r = __builtin_amdgcn_cvt_pk_bf16_f32(a, b);
    return __builtin_bit_cast(unsigned, r);
#else
    return (unsigned)f2bf(a) | ((unsigned)f2bf(b) << 16);
#endif
}
// Fast activations: v_rcp_f32 (1 ulp) instead of the IEEE div sequence.
__device__ __forceinline__ float frcp(float x)   { return __builtin_amdgcn_rcpf(x); }
__device__ __forceinline__ float sigm(float x)   { return frcp(1.0f + __expf(-x)); }
__device__ __forceinline__ float tanhf_(float x) { return 1.0f - 2.0f * frcp(1.0f + __expf(2.0f * x)); }

// Opaque-def pin: blocks rematerialization of the one-time weight loads.
__device__ __forceinline__ void pin(bf16x8& v) { asm volatile("" : "+v"(v)); }

// LDS-only barrier: cross-wave dependence inside the t-loop is LDS only.
#define LDS_BARRIER() asm volatile("s_waitcnt lgkmcnt(0)\ns_barrier" ::: "memory")

#define MFMA(acc, a, b) acc = __builtin_amdgcn_mfma_f32_16x16x32_bf16(a, b, acc, 0, 0, 0)

// One LSTM elementwise h-value (10 trans). Compile-time v via macro expansion.
#define ELEMV(accX, csX, v, dst) { \
    float ig_ = sigm(accX[0][v]); \
    float fg_ = sigm(accX[1][v]); \
    float gg_ = tanhf_(accX[2][v]); \
    float og_ = sigm(accX[3][v]); \
    float c_  = fg_ * csX[v] + ig_ * gg_; \
    csX[v] = c_; \
    dst = og_ * tanhf_(c_); }

// Pack 2 h-values and write into frag-order XOR layout (rows r0, r0+1).
#define WRPAIR(hdst, r0, h0, h1) { \
    unsigned u_ = pkbf2(h0, h1); \
    int b0_ = quad*4 + (r0); \
    (hdst)[b0_*128     + ((jc ^ b0_)*8)     + jl] = (unsigned short)u_; \
    (hdst)[(b0_+1)*128 + ((jc ^ (b0_+1))*8) + jl] = (unsigned short)(u_ >> 16); }

// Pack weights into exact B-fragment order: B[k][n], n = lane&15, k = (lane>>4)*8 + j.
__global__ void prep(const float* __restrict__ Wih0, const float* __restrict__ Whh0,
                     const float* __restrict__ bih0, const float* __restrict__ bhh0,
                     const float* __restrict__ Wih1, const float* __restrict__ Whh1,
                     const float* __restrict__ bih1, const float* __restrict__ bhh1,
                     unsigned short* __restrict__ W, float* __restrict__ bias) {
    int i = blockIdx.x * 256 + threadIdx.x;
    if (i < NW0E) {
        int ut = i / (20*512), r = i % (20*512);
        int f = r >> 9, e = r & 511;
        int lane = e >> 3, j = e & 7;
        int lrow = lane & 15, quad = lane >> 4;
        float v;
        if (f < 4) {                        // x-part: K=28 padded to 32
            int gt = f, k = quad*8 + j;
            int g = gt*128 + ut*16 + lrow;
            v = (k < D_IN) ? Wih0[g*D_IN + k] : 0.0f;
        } else {                            // h0-part: 4 K-steps
            int ks = (f-4) >> 2, gt = (f-4) & 3;
            int g = gt*128 + ut*16 + lrow;
            v = Whh0[g*H + ks*32 + quad*8 + j];
        }
        W[i] = f2bf(v);
    } else if (i < NW0E + NW1E) {
        int i2 = i - NW0E;
        int ut = i2 / (32*512), r = i2 % (32*512);
        int f = r >> 9, e = r & 511;
        int lane = e >> 3, j = e & 7;
        int lrow = lane & 15, quad = lane >> 4;
        int ks = f >> 2, gt = f & 3;        // ks 0..3 = Wih1, 4..7 = Whh1
        int g = gt*128 + ut*16 + lrow;
        float v = (ks < 4) ? Wih1[g*H + ks*32 + quad*8 + j]
                           : Whh1[g*H + (ks-4)*32 + quad*8 + j];
        W[i] = f2bf(v);
    } else if (i < NW0E + NW1E + 1024) {
        int g = i - NW0E - NW1E;
        if (g < 512) bias[g] = bih0[g] + bhh0[g];
        else         bias[g] = bih1[g-512] + bhh1[g-512];
    }
}

// ================= Phase kernels ==========
// h0seq layout: [bt16:512][t:28][cc:4][lane:64][el:8] bf16 — exact A-frag order.
//
// R7: 16-WAVE l0 THAT FITS. R6 proved the occupancy lever (1024-thr block ->
// 44.8% occ, 4 waves/SIMD) but spilled: waves_per_eu(4,4) budget is 128
// unified and 80 pinned weight VGPRs + acc + working set overflowed
// (VGPR_Count=64, FETCH 200MB = spill + L1-thrash on ut-redundant x loads).
// Fix: x-part weight frags (4) go to LDS (wxl, 32 KB, proven R0 pattern,
// 0 bank conflicts); only the 16 recurrent frags stay pinned (64 VGPR).
// Est. per-wave: 64 wh + 16 acc + 8 x + ~20 misc ~= 110 < 128 -> no spill.

// Layer 0: grid 256, BT=32, NTHR0=1024, waves 0-7 tile A, 8-15 tile B.
__global__ __attribute__((amdgpu_waves_per_eu(4, 4))) __launch_bounds__(NTHR0)
void lstm_l0(
    const float* __restrict__ x, const unsigned short* __restrict__ W,
    const float* __restrict__ bias, unsigned short* __restrict__ h0seq)
{
    __shared__ __align__(16) unsigned short hA[2][16*128];   // 8 KB (double buffer)
    __shared__ __align__(16) unsigned short hB[2][16*128];   // 8 KB
    __shared__ __align__(16) unsigned short wxl[8*4*512];    // 32 KB: W0 x-part frags

    const int tid = threadIdx.x, lane = tid & 63;
    const int w   = tid >> 6;            // wave 0..15
    const int g   = w >> 3;              // tile group: 0 = A, 1 = B
    const int ut  = w & 7;               // column-slice (same weights for both groups)
    const int lrow = lane & 15, quad = lane >> 4;
    const int blk = blockIdx.x;          // 0..255
    const int bbase = blk * 32;

    for (int i = tid; i < 16*128; i += NTHR0) {
        hA[0][i] = 0; hA[1][i] = 0; hB[0][i] = 0; hB[1][i] = 0;
    }
#pragma unroll
    for (int it = 0; it < 2; ++it) {     // stage x-part frags (16384 ushorts)
        int i = it*NTHR0 + tid;          // chunk id 0..2047
        int utw = i >> 8, rest = i & 255, f = rest >> 6, l8 = rest & 63;
        *(bf16x8*)&wxl[utw*2048 + f*512 + l8*8] =
            *(const bf16x8*)&W[utw*10240 + f*512 + l8*8];
    }

    const unsigned short* w0p = W + ut*10240 + lane*8;
    bf16x8 wh[16];
#pragma unroll
    for (int f = 0; f < 16; ++f) { wh[f] = *(const bf16x8*)(w0p + (4+f)*512); pin(wh[f]); }

    float cs[4] = {0.f,0.f,0.f,0.f};
    float bv[4];
#pragma unroll
    for (int gt = 0; gt < 4; ++gt) bv[gt] = bias[gt*128 + ut*16 + lrow];

    const float* xr = x + (size_t)(bbase + g*16 + lrow) * (T_SEQ*D_IN) + quad*8;
    const int jc = (ut*16 + lrow) >> 3, jl = (ut*16 + lrow) & 7;

    // store mapping: waves {0-3} store tile A, waves {8-11} store tile B
    const bool sstore = ((w & 4) == 0);
    const int scc = w & 3;               // cc 0..3 within tile
    const int sq2 = lane >> 4, sb = lane & 15;
    const int schunk = (scc*4 + sq2) ^ sb;
    unsigned short* sdst = h0seq + (size_t)(2*blk + g)*(T_SEQ*2048) + scc*512 + lane*8;

#define L0_LDH(hrd_, ks_) (*(const bf16x8*)&(hrd_)[lrow*128 + ((((ks_)*4 + quad) ^ lrow)*8)])
#define L0_KS(accX, ah_, ks_) { \
        MFMA(accX[0], ah_, wh[(ks_)*4+0]); \
        MFMA(accX[1], ah_, wh[(ks_)*4+1]); \
        MFMA(accX[2], ah_, wh[(ks_)*4+2]); \
        MFMA(accX[3], ah_, wh[(ks_)*4+3]); }

    // preload x(t=0) for this wave's tile
    float4 lo = *(const float4*)xr;
    float4 hi = make_float4(0.f,0.f,0.f,0.f);
    if (quad < 3) hi = *(const float4*)(xr+4);

    __syncthreads();                     // hbuf zero + wxl staging visible

#pragma unroll 1
    for (int t = 0; t < T_SEQ; ++t) {
        const int rdi = (t+1) & 1, wri = t & 1;     // read h(t-1), write h(t)
        const unsigned short* hrd = g ? hB[rdi] : hA[rdi];
        unsigned short* hwr = g ? hB[wri] : hA[wri];

        // store h(t-1) to h0seq (rd buffer, RO this segment)
        if (t > 0 && sstore) {
            bf16x8 hv = *(const bf16x8*)&hrd[sb*128 + schunk*8];
            *(bf16x8*)(sdst + (size_t)(t-1)*2048) = hv;
        }

        // hoist the 4 h A-frag ds_reads
        bf16x8 ah0 = L0_LDH(hrd, 0), ah1 = L0_LDH(hrd, 1);
        bf16x8 ah2 = L0_LDH(hrd, 2), ah3 = L0_LDH(hrd, 3);

        u32x4 ua;
        ua[0]=pkbf2(lo.x,lo.y); ua[1]=pkbf2(lo.z,lo.w);
        ua[2]=pkbf2(hi.x,hi.y); ua[3]=pkbf2(hi.z,hi.w);
        bf16x8 ax = __builtin_bit_cast(bf16x8, ua);

        f32x4 acc[4];
#pragma unroll
        for (int gt = 0; gt < 4; ++gt) { f32x4 s = {bv[gt],bv[gt],bv[gt],bv[gt]}; acc[gt] = s; }
        // x part (LDS weights, loaded per-MFMA to keep transient pressure low;
        // 4 waves/SIMD TLP covers the lgkm waits)
#pragma unroll
        for (int gt = 0; gt < 4; ++gt) {
            bf16x8 wf = *(const bf16x8*)&wxl[ut*2048 + gt*512 + lane*8];
            MFMA(acc[gt], ax, wf);
        }
        // recurrent part (pinned reg weights)
        L0_KS(acc, ah0, 0);
        L0_KS(acc, ah1, 1);
        L0_KS(acc, ah2, 2);
        L0_KS(acc, ah3, 3);

        // prefetch x(t+1) — latency hidden under elem + cross-wave overlap
        if (t + 1 < T_SEQ) {
            const float* p = xr + (t+1)*D_IN;
            lo = *(const float4*)p;
            hi = make_float4(0.f,0.f,0.f,0.f);
            if (quad < 3) hi = *(const float4*)(p+4);
        }

        // elementwise -> wr buffer
        {
            float h0, h1;
            ELEMV(acc, cs, 0, h0); ELEMV(acc, cs, 1, h1); WRPAIR(hwr, 0, h0, h1);
            ELEMV(acc, cs, 2, h0); ELEMV(acc, cs, 3, h1); WRPAIR(hwr, 2, h0, h1);
        }

        LDS_BARRIER();
    }

    // final store h(T-1): buf[1] (27&1==1); last barrier already executed
    if (sstore) {
        const unsigned short* hrd = g ? hB[1] : hA[1];
        bf16x8 hv = *(const bf16x8*)&hrd[sb*128 + schunk*8];
        *(bf16x8*)(sdst + (size_t)(T_SEQ-1)*2048) = hv;
    }
#undef L0_LDH
#undef L0_KS
}

// Layer 1 + FC + log_softmax: grid 256, lockstep 2-tile, one barrier/t.
// (unchanged — 128 pinned weight VGPRs preclude the 4-wave budget; redesign
// only if l0's fixed 16-wave experiment validates the latency-hiding gain.)
__global__ __attribute__((amdgpu_waves_per_eu(2, 2))) __launch_bounds__(NTHR)
void lstm_l1(
    const unsigned short* __restrict__ h0seq, const unsigned short* __restrict__ W,
    const float* __restrict__ bias, const float* __restrict__ Wfc,
    const float* __restrict__ bfc, float* __restrict__ out)
{
    __shared__ __align__(16) unsigned short hA[2][16*128];   // 8 KB
    __shared__ __align__(16) unsigned short hB[2][16*128];   // 8 KB
    __shared__ float lg[320];

    const int tid = threadIdx.x, lane = tid & 63, ut = tid >> 6;
    const int lrow = lane & 15, quad = lane >> 4;
    const int blk = blockIdx.x;
    const int bbase = blk * 32;

    for (int i = tid; i < 16*128; i += NTHR) {
        hA[0][i] = 0; hA[1][i] = 0; hB[0][i] = 0; hB[1][i] = 0;
    }

    const unsigned short* w1p = W + NW0E + ut*16384 + lane*8;
    bf16x8 w1a[16], w1b[16];                 // Wih1 (ks0..3), Whh1 (ks4..7)
#pragma unroll
    for (int f = 0; f < 16; ++f) { w1a[f] = *(const bf16x8*)(w1p + f*512);        pin(w1a[f]); }
#pragma unroll
    for (int f = 0; f < 16; ++f) { w1b[f] = *(const bf16x8*)(w1p + (16+f)*512);   pin(w1b[f]); }

    float cA[4] = {0.f,0.f,0.f,0.f}, cB[4] = {0.f,0.f,0.f,0.f};
    float bv1[4];
#pragma unroll
    for (int gt = 0; gt < 4; ++gt) bv1[gt] = bias[512 + gt*128 + ut*16 + lrow];

    const unsigned short* sqA = h0seq + (size_t)(2*blk)   * (T_SEQ*2048) + lane*8;
    const unsigned short* sqB = h0seq + (size_t)(2*blk+1) * (T_SEQ*2048) + lane*8;
    const int jc = (ut*16 + lrow) >> 3, jl = (ut*16 + lrow) & 7;

#define L1_LDH(hrd_, ks_) (*(const bf16x8*)&(hrd_)[lrow*128 + ((((ks_)*4 + quad) ^ lrow)*8)])
#define L1_XS(accX, ga_, cc_) { \
        MFMA(accX[0], ga_[cc_], w1a[(cc_)*4+0]); \
        MFMA(accX[1], ga_[cc_], w1a[(cc_)*4+1]); \
        MFMA(accX[2], ga_[cc_], w1a[(cc_)*4+2]); \
        MFMA(accX[3], ga_[cc_], w1a[(cc_)*4+3]); }
#define L1_HS(accX, ah_, ks_) { \
        MFMA(accX[0], ah_, w1b[(ks_)*4+0]); \
        MFMA(accX[1], ah_, w1b[(ks_)*4+1]); \
        MFMA(accX[2], ah_, w1b[(ks_)*4+2]); \
        MFMA(accX[3], ah_, w1b[(ks_)*4+3]); }

    // preload ga(t=0) for both tiles
    bf16x8 gaA[4], gaB[4];
#pragma unroll
    for (int cc = 0; cc < 4; ++cc) gaA[cc] = *(const bf16x8*)(sqA + cc*512);
#pragma unroll
    for (int cc = 0; cc < 4; ++cc) gaB[cc] = *(const bf16x8*)(sqB + cc*512);

    __syncthreads();

#pragma unroll 1
    for (int t = 0; t < T_SEQ; ++t) {
        const int rdi = (t+1) & 1, wri = t & 1;
        const unsigned short* hArd = hA[rdi];
        const unsigned short* hBrd = hB[rdi];

        // hoist all 8 A-frag ds_reads
        bf16x8 ah0 = L1_LDH(hArd, 0), ah1 = L1_LDH(hArd, 1);
        bf16x8 ah2 = L1_LDH(hArd, 2), ah3 = L1_LDH(hArd, 3);
        bf16x8 bh0 = L1_LDH(hBrd, 0), bh1 = L1_LDH(hBrd, 1);
        bf16x8 bh2 = L1_LDH(hBrd, 2), bh3 = L1_LDH(hBrd, 3);

        f32x4 accA[4], accB[4];
#pragma unroll
        for (int gt = 0; gt < 4; ++gt) {
            f32x4 s = {bv1[gt],bv1[gt],bv1[gt],bv1[gt]};
            accA[gt] = s; accB[gt] = s;
        }
        // x-part (register operands) first
        L1_XS(accA, gaA, 0); L1_XS(accB, gaB, 0);
        L1_XS(accA, gaA, 1); L1_XS(accB, gaB, 1);
        L1_XS(accA, gaA, 2); L1_XS(accB, gaB, 2);
        L1_XS(accA, gaA, 3); L1_XS(accB, gaB, 3);
        // h-part
        L1_HS(accA, ah0, 0); L1_HS(accB, bh0, 0);
        L1_HS(accA, ah1, 1); L1_HS(accB, bh1, 1);
        L1_HS(accA, ah2, 2); L1_HS(accB, bh2, 2);
        L1_HS(accA, ah3, 3); L1_HS(accB, bh3, 3);

        // prefetch ga(t+1)
        if (t + 1 < T_SEQ) {
#pragma unroll
            for (int cc = 0; cc < 4; ++cc) gaA[cc] = *(const bf16x8*)(sqA + (t+1)*2048 + cc*512);
#pragma unroll
            for (int cc = 0; cc < 4; ++cc) gaB[cc] = *(const bf16x8*)(sqB + (t+1)*2048 + cc*512);
        }

        // elementwise both tiles -> wr buffers
        {
            float h0, h1;
            ELEMV(accA, cA, 0, h0); ELEMV(accA, cA, 1, h1); WRPAIR(hA[wri], 0, h0, h1);
            ELEMV(accA, cA, 2, h0); ELEMV(accA, cA, 3, h1); WRPAIR(hA[wri], 2, h0, h1);
            ELEMV(accB, cB, 0, h0); ELEMV(accB, cB, 1, h1); WRPAIR(hB[wri], 0, h0, h1);
            ELEMV(accB, cB, 2, h0); ELEMV(accB, cB, 3, h1); WRPAIR(hB[wri], 2, h0, h1);
        }

        LDS_BARRIER();
    }

    // FC + log_softmax. h1(T-1) in buf[1] (T-1=27). Last barrier already done.
    if (tid < 320) {
        int c = tid >> 5, b = tid & 31;
        int bl = b & 15;
        const unsigned short* hs = (b < 16) ? hA[1] : hB[1];
        float s = bfc[c];
        const float* wr = Wfc + c*H;
#pragma unroll
        for (int j8 = 0; j8 < 16; ++j8) {        // vectorized LDS read (bf16x8)
            bf16x8 hv = *(const bf16x8*)&hs[bl*128 + ((j8 ^ bl)*8)];
#pragma unroll
            for (int k = 0; k < 8; ++k)
                s = fmaf(wr[j8*8 + k], bf2f((unsigned short)hv[k]), s);
        }
        lg[c*32 + b] = s;
    }
    __syncthreads();
    if (tid < 32) {
        int b = tid;
        float m = -1e30f;
#pragma unroll
        for (int c = 0; c < 10; ++c) m = fmaxf(m, lg[c*32 + b]);
        float ssum = 0.f;
#pragma unroll
        for (int c = 0; c < 10; ++c) ssum += __expf(lg[c*32 + b] - m);
        float ls = m + __logf(ssum);
        float* op = out + (size_t)(bbase + b) * 10;
#pragma unroll
        for (int c = 0; c < 10; ++c) op[c] = lg[c*32 + b] - ls;
    }
#undef L1_LDH
#undef L1_XS
#undef L1_HS
}

// ================= Monolithic fallback =====================
__global__ __attribute__((amdgpu_waves_per_eu(2, 2))) __launch_bounds__(NTHR)
void lstm_mfma(
    const float* __restrict__ x, const unsigned short* __restrict__ W,
    const float* __restrict__ bias,
    const float* __restrict__ Wfc, const float* __restrict__ bfc,
    float* __restrict__ out)
{
    __shared__ __align__(16) unsigned short h0s[2][32*128];
    __shared__ __align__(16) unsigned short h1s[32*128];
    __shared__ __align__(16) unsigned short wl[8*16*512];

    const int tid  = threadIdx.x;
    const int lane = tid & 63;
    const int ut   = tid >> 6;
    const int lrow = lane & 15;
    const int quad = lane >> 4;
    const int bbase = blockIdx.x * 32;

    for (int i = tid; i < 32*128; i += NTHR) { h0s[0][i] = 0; h0s[1][i] = 0; h1s[i] = 0; }
#pragma unroll
    for (int it = 0; it < 16; ++it) {
        int i = it * (NTHR*8) + tid*8;
        int utw = i >> 13, r = i & 8191;
        *(bf16x8*)&wl[i] = *(const bf16x8*)&W[NW0E + utw*16384 + 8192 + r];
    }
    const unsigned short* w0p = W + ut*(20*512) + lane*8;
    const unsigned short* w1p = W + NW0E + ut*(32*512) + lane*8;
    bf16x8 w0x[4], w0h[16], w1h[16];
#pragma unroll
    for (int f = 0; f < 4; ++f)  w0x[f] = *(const bf16x8*)(w0p + f*512);
#pragma unroll
    for (int f = 0; f < 16; ++f) w0h[f] = *(const bf16x8*)(w0p + (4+f)*512);
#pragma unroll
    for (int f = 0; f < 16; ++f) w1h[f] = *(const bf16x8*)(w1p + f*512);

    float c0[2][4], c1[2][4];
#pragma unroll
    for (int m = 0; m < 2; ++m)
#pragma unroll
        for (int r = 0; r < 4; ++r) { c0[m][r] = 0.f; c1[m][r] = 0.f; }
    float bv0[4], bv1[4];
#pragma unroll
    for (int gt = 0; gt < 4; ++gt) {
        bv0[gt] = bias[gt*128 + ut*16 + lrow];
        bv1[gt] = bias[512 + gt*128 + ut*16 + lrow];
    }
    const float* xr0 = x + (size_t)(bbase + lrow)      * (T_SEQ*D_IN) + quad*8;
    const float* xr1 = x + (size_t)(bbase + 16 + lrow) * (T_SEQ*D_IN) + quad*8;
    const int jc = (ut*16 + lrow) >> 3;
    const int jl = (ut*16 + lrow) & 7;
    __syncthreads();

    auto step = [&](const unsigned short* __restrict__ h0rd,
                    unsigned short* __restrict__ h0wr, int t) {
        f32x4 acc[2][4];
#pragma unroll
        for (int gt = 0; gt < 4; ++gt) {
            f32x4 s = {bv0[gt], bv0[gt], bv0[gt], bv0[gt]};
            acc[0][gt] = s; acc[1][gt] = s;
        }
        {
            const float* p0 = xr0 + t*D_IN;
            const float* p1 = xr1 + t*D_IN;
            float4 lo0 = *(const float4*)p0;
            float4 lo1 = *(const float4*)p1;
            float4 hi0 = make_float4(0,0,0,0), hi1 = make_float4(0,0,0,0);
            if (quad < 3) { hi0 = *(const float4*)(p0+4); hi1 = *(const float4*)(p1+4); }
            u32x4 ua0, ua1;
            ua0[0] = pkbf2(lo0.x, lo0.y); ua0[1] = pkbf2(lo0.z, lo0.w);
            ua0[2] = pkbf2(hi0.x, hi0.y); ua0[3] = pkbf2(hi0.z, hi0.w);
            ua1[0] = pkbf2(lo1.x, lo1.y); ua1[1] = pkbf2(lo1.z, lo1.w);
            ua1[2] = pkbf2(hi1.x, hi1.y); ua1[3] = pkbf2(hi1.z, hi1.w);
            bf16x8 a0 = __builtin_bit_cast(bf16x8, ua0);
            bf16x8 a1 = __builtin_bit_cast(bf16x8, ua1);
#pragma unroll
            for (int gt = 0; gt < 4; ++gt) {
                MFMA(acc[0][gt], a0, w0x[gt]);
                MFMA(acc[1][gt], a1, w0x[gt]);
            }
        }
#pragma unroll
        for (int ks = 0; ks < 4; ++ks) {
            int cc = ks*4 + quad;
            bf16x8 a0 = *(const bf16x8*)&h0rd[lrow*128      + ((cc ^ lrow)*8)];
            bf16x8 a1 = *(const bf16x8*)&h0rd[(16+lrow)*128 + ((cc ^ lrow)*8)];
#pragma unroll
            for (int gt = 0; gt < 4; ++gt) {
                MFMA(acc[0][gt], a0, w0h[ks*4+gt]);
                MFMA(acc[1][gt], a1, w0h[ks*4+gt]);
            }
        }
#pragma unroll
        for (int m = 0; m < 2; ++m) {
#pragma unroll
            for (int r = 0; r < 4; r += 2) {
                float hv[2];
#pragma unroll
                for (int q = 0; q < 2; ++q) {
                    float ig = sigm(acc[m][0][r+q]);
                    float fg = sigm(acc[m][1][r+q]);
                    float gg = tanhf_(acc[m][2][r+q]);
                    float og = sigm(acc[m][3][r+q]);
                    float c  = fg * c0[m][r+q] + ig * gg;
                    c0[m][r+q] = c;
                    hv[q] = og * tanhf_(c);
                }
                unsigned u = pkbf2(hv[0], hv[1]);
                int b0 = m*16 + quad*4 + r;
                h0wr[b0*128     + ((jc ^ (b0&15))*8)     + jl] = (unsigned short)u;
                h0wr[(b0+1)*128 + ((jc ^ ((b0+1)&15))*8) + jl] = (unsigned short)(u >> 16);
            }
        }
        __syncthreads();
#pragma unroll
        for (int gt = 0; gt < 4; ++gt) {
            f32x4 s = {bv1[gt], bv1[gt], bv1[gt], bv1[gt]};
            acc[0][gt] = s; acc[1][gt] = s;
        }
#pragma unroll
        for (int ks = 0; ks < 4; ++ks) {
            int cc = ks*4 + quad;
            bf16x8 a0 = *(const bf16x8*)&h0wr[lrow*128      + ((cc ^ lrow)*8)];
            bf16x8 a1 = *(const bf16x8*)&h0wr[(16+lrow)*128 + ((cc ^ lrow)*8)];
#pragma unroll
            for (int gt = 0; gt < 4; ++gt) {
                MFMA(acc[0][gt], a0, w1h[ks*4+gt]);
                MFMA(acc[1][gt], a1, w1h[ks*4+gt]);
            }
        }
#pragma unroll
        for (int ks = 0; ks < 4; ++ks) {
            int cc = ks*4 + quad;
            bf16x8 a0 = *(const bf16x8*)&h1s[lrow*128      + ((cc ^ lrow)*8)];
            bf16x8 a1 = *(const bf16x8*)&h1s[(16+lrow)*128 + ((cc ^ lrow)*8)];
#pragma unroll
            for (int gt = 0; gt < 4; ++gt) {
                bf16x8 bf = *(const bf16x8*)&wl[ut*8192 + (ks*4+gt)*512 + lane*8];
                MFMA(acc[0][gt], a0, bf);
                MFMA(acc[1][gt], a1, bf);
            }
        }
        __syncthreads();
#pragma unroll
        for (int m = 0; m < 2; ++m) {
#pragma unroll
            for (int r = 0; r < 4; r += 2) {
                float hv[2];
#pragma unroll
                for (int q = 0; q < 2; ++q) {
                    float ig = sigm(acc[m][0][r+q]);
                    float fg = sigm(acc[m][1][r+q]);
                    float gg = tanhf_(acc[m][2][r+q]);
                    float og = sigm(acc[m][3][r+q]);
                    float c  = fg * c1[m][r+q] + ig * gg;
                    c1[m][r+q] = c;
                    hv[q] = og * tanhf_(c);
                }
                unsigned u = pkbf2(hv[0], hv[1]);
                int b0 = m*16 + quad*4 + r;
                h1s[b0*128     + ((jc ^ (b0&15))*8)     + jl] = (unsigned short)u;
                h1s[(b0+1)*128 + ((jc ^ ((b0+1)&15))*8) + jl] = (unsigned short)(u >> 16);
            }
        }
    };
#pragma unroll 1
    for (int t2 = 0; t2 < T_SEQ/2; ++t2) {
        step(h0s[0], h0s[1], 2*t2);
        step(h0s[1], h0s[0], 2*t2 + 1);
    }
    __syncthreads();
    float* lg = (float*)&h0s[0][0];
    if (tid < 320) {
        int c = tid >> 5, b = tid & 31;
        float s = bfc[c];
        const float* wr = Wfc + c*H;
#pragma unroll 4
        for (int j = 0; j < H; ++j)
            s = fmaf(wr[j], bf2f(h1s[b*128 + (((j>>3) ^ (b&15))*8) + (j&7)]), s);
        lg[c*32 + b] = s;
    }
    __syncthreads();
    if (tid < 32) {
        int b = tid;
        float m = -1e30f;
#pragma unroll
        for (int c = 0; c < 10; ++c) m = fmaxf(m, lg[c*32 + b]);
        float ssum = 0.f;
#pragma unroll
        for (int c = 0; c < 10; ++c) ssum += __expf(lg[c*32 + b] - m);
        float ls = m + __logf(ssum);
        float* op = out + (size_t)(bbase + b) * 10;
#pragma unroll
        for (int c = 0; c < 10; ++c) op[c] = lg[c*32 + b] - ls;
    }
}

extern "C" void kernel_launch(void* const* d_in, const int* in_sizes, int n_in,
                              void* d_out, int out_size, void* d_ws, size_t ws_size,
                              hipStream_t stream) {
    const float* x    = (const float*)d_in[0];
    const float* Wih0 = (const float*)d_in[1];
    const float* Whh0 = (const float*)d_in[2];
    const float* bih0 = (const float*)d_in[3];
    const float* bhh0 = (const float*)d_in[4];
    const float* Wih1 = (const float*)d_in[5];
    const float* Whh1 = (const float*)d_in[6];
    const float* bih1 = (const float*)d_in[7];
    const float* bhh1 = (const float*)d_in[8];
    const float* Wfc  = (const float*)d_in[9];
    const float* bfc  = (const float*)d_in[10];
    float* out = (float*)d_out;

    unsigned short* W = (unsigned short*)d_ws;
    float* bias = (float*)((char*)d_ws + BIAS_OFF_BYTES);

    const int n_prep = NW0E + NW1E + 1024;
    prep<<<(n_prep + 255) / 256, 256, 0, stream>>>(Wih0, Whh0, bih0, bhh0,
                                                   Wih1, Whh1, bih1, bhh1, W, bias);
    if (ws_size >= (size_t)NEED_WS) {
        unsigned short* h0seq = (unsigned short*)((char*)d_ws + SEQ_OFF_BYTES);
        lstm_l0<<<256, NTHR0, 0, stream>>>(x, W, bias, h0seq);
        lstm_l1<<<256, NTHR, 0, stream>>>(h0seq, W, bias, Wfc, bfc, out);
    } else {
        lstm_mfma<<<256, NTHR, 0, stream>>>(x, W, bias, Wfc, bfc, out);
    }
}

// Round 9
// 211.981 us; speedup vs baseline: 1.4025x; 1.1772x over previous
//
#include <hip/hip_runtime.h>
#include <math.h>

#define T_SEQ 28
#define D_IN  28
#define H     128
#define NTHR  512

typedef short bf16x8 __attribute__((ext_vector_type(8)));   // 8 bf16 = 4 VGPR (A/B frag)
typedef short bf16x2 __attribute__((ext_vector_type(2)));
typedef float f32x4  __attribute__((ext_vector_type(4)));   // C/D frag
typedef unsigned u32x4 __attribute__((ext_vector_type(4)));

// ws layout: W0 frags [ut][f0:20][lane][8] | W1 frags [ut][f1:32][lane][8] | biases fp32 | h0seq
#define NW0E (8*20*512)                     // 81920 ushorts
#define NW1E (8*32*512)                     // 131072 ushorts
#define BIAS_OFF_BYTES ((NW0E + NW1E) * 2)  // 425984 B
#define SEQ_OFF_BYTES  (BIAS_OFF_BYTES + 4096)
#define SEQ_ELEMS      ((size_t)512 * T_SEQ * 2048)          // bf16 elements
#define NEED_WS        (SEQ_OFF_BYTES + SEQ_ELEMS * 2)       // ~59.2 MB

__device__ __forceinline__ unsigned short f2bf(float f) {
    unsigned u = __float_as_uint(f);
    u += 0x7fffu + ((u >> 16) & 1u);        // round-to-nearest-even
    return (unsigned short)(u >> 16);
}
__device__ __forceinline__ float bf2f(unsigned short h) {
    return __uint_as_float(((unsigned)h) << 16);
}
__device__ __forceinline__ unsigned pkbf2(float a, float b) {
#if __has_builtin(__builtin_amdgcn_cvt_pk_bf16_f32)
    bf16x2 r = __builtin_amdgcn_cvt_pk_bf16_f32(a, b);
    return __builtin_bit_cast(unsigned, r);
#else
    return (unsigned)f2bf(a) | ((unsigned)f2bf(b) << 16);
#endif
}
// Fast activations: v_rcp_f32 (1 ulp) instead of the IEEE div sequence.
__device__ __forceinline__ float frcp(float x)   { return __builtin_amdgcn_rcpf(x); }
__device__ __forceinline__ float sigm(float x)   { return frcp(1.0f + __expf(-x)); }
__device__ __forceinline__ float tanhf_(float x) { return 1.0f - 2.0f * frcp(1.0f + __expf(2.0f * x)); }

// Opaque-def pin: blocks rematerialization of the one-time weight loads.
// NOTE (R8 post-mortem): "+a" (AGPR) pin on a 16B vector MISCOMPILES (NaN).
// Only "+v" is safe. At waves_per_eu(2,2) the unified file is 256/wave:
// the "+v" pins fill the arch half, MFMA accumulators live in the acc half.
__device__ __forceinline__ void pin(bf16x8& v)  { asm volatile("" : "+v"(v)); }

// LDS-only barrier: cross-wave dependence inside the t-loop is LDS only.
#define LDS_BARRIER() asm volatile("s_waitcnt lgkmcnt(0)\ns_barrier" ::: "memory")

#define MFMA(acc, a, b) acc = __builtin_amdgcn_mfma_f32_16x16x32_bf16(a, b, acc, 0, 0, 0)

// One LSTM elementwise h-value (10 trans). Compile-time v via macro expansion.
#define ELEMV(accX, csX, v, dst) { \
    float ig_ = sigm(accX[0][v]); \
    float fg_ = sigm(accX[1][v]); \
    float gg_ = tanhf_(accX[2][v]); \
    float og_ = sigm(accX[3][v]); \
    float c_  = fg_ * csX[v] + ig_ * gg_; \
    csX[v] = c_; \
    dst = og_ * tanhf_(c_); }

// Pack 2 h-values and write into frag-order XOR layout (rows r0, r0+1).
#define WRPAIR(hdst, r0, h0, h1) { \
    unsigned u_ = pkbf2(h0, h1); \
    int b0_ = quad*4 + (r0); \
    (hdst)[b0_*128     + ((jc ^ b0_)*8)     + jl] = (unsigned short)u_; \
    (hdst)[(b0_+1)*128 + ((jc ^ (b0_+1))*8) + jl] = (unsigned short)(u_ >> 16); }

// Pack weights into exact B-fragment order: B[k][n], n = lane&15, k = (lane>>4)*8 + j.
__global__ void prep(const float* __restrict__ Wih0, const float* __restrict__ Whh0,
                     const float* __restrict__ bih0, const float* __restrict__ bhh0,
                     const float* __restrict__ Wih1, const float* __restrict__ Whh1,
                     const float* __restrict__ bih1, const float* __restrict__ bhh1,
                     unsigned short* __restrict__ W, float* __restrict__ bias) {
    int i = blockIdx.x * 256 + threadIdx.x;
    if (i < NW0E) {
        int ut = i / (20*512), r = i % (20*512);
        int f = r >> 9, e = r & 511;
        int lane = e >> 3, j = e & 7;
        int lrow = lane & 15, quad = lane >> 4;
        float v;
        if (f < 4) {                        // x-part: K=28 padded to 32
            int gt = f, k = quad*8 + j;
            int g = gt*128 + ut*16 + lrow;
            v = (k < D_IN) ? Wih0[g*D_IN + k] : 0.0f;
        } else {                            // h0-part: 4 K-steps
            int ks = (f-4) >> 2, gt = (f-4) & 3;
            int g = gt*128 + ut*16 + lrow;
            v = Whh0[g*H + ks*32 + quad*8 + j];
        }
        W[i] = f2bf(v);
    } else if (i < NW0E + NW1E) {
        int i2 = i - NW0E;
        int ut = i2 / (32*512), r = i2 % (32*512);
        int f = r >> 9, e = r & 511;
        int lane = e >> 3, j = e & 7;
        int lrow = lane & 15, quad = lane >> 4;
        int ks = f >> 2, gt = f & 3;        // ks 0..3 = Wih1, 4..7 = Whh1
        int g = gt*128 + ut*16 + lrow;
        float v = (ks < 4) ? Wih1[g*H + ks*32 + quad*8 + j]
                           : Whh1[g*H + (ks-4)*32 + quad*8 + j];
        W[i] = f2bf(v);
    } else if (i < NW0E + NW1E + 1024) {
        int g = i - NW0E - NW1E;
        if (g < 512) bias[g] = bih0[g] + bhh0[g];
        else         bias[g] = bih1[g-512] + bhh1[g-512];
    }
}

// ================= Phase kernels ==========
// h0seq layout: [bt16:512][t:28][cc:4][lane:64][el:8] bf16 — exact A-frag order.
//
// R9: PEELED OFFSET-PHASE + UNGUARDED INTERLEAVE. Evidence: R4 interleave
// helped l1 (78->69, few guards) and hurt l0 (85, guards around EVERY elem
// cluster + VGPR growth). R8's AGPR pin miscompiled (NaN) -> reverted; both
// kernels back to proven 512-thr waves_per_eu(2,2). New single variable:
// peel seg_a(0) out of the loop so the steady-state body
//   [seg_b(t): MFMA_B(t)+elem_A(t) ; seg_a(t+1): MFMA_A(t+1)+elem_B(t)]
// has ZERO elem guards. Math is value-identical to all passing rounds.

// Layer 0: grid 256, BT=32 (tiles A rows 0-15, B rows 16-31), 20 W0 frags
// pinned (80 arch VGPR), single-buffered hA/hB (RO/WO alternates per seg).
__global__ __attribute__((amdgpu_waves_per_eu(2, 2))) __launch_bounds__(NTHR)
void lstm_l0(
    const float* __restrict__ x, const unsigned short* __restrict__ W,
    const float* __restrict__ bias, unsigned short* __restrict__ h0seq)
{
    __shared__ __align__(16) unsigned short hA[16*128];   // 4 KB
    __shared__ __align__(16) unsigned short hB[16*128];   // 4 KB

    const int tid = threadIdx.x, lane = tid & 63, ut = tid >> 6;
    const int lrow = lane & 15, quad = lane >> 4;
    const int blk = blockIdx.x;          // 0..255
    const int bbase = blk * 32;

    for (int i = tid; i < 16*128; i += NTHR) { hA[i] = 0; hB[i] = 0; }

    const unsigned short* w0p = W + ut*10240 + lane*8;
    bf16x8 wxf[4];
#pragma unroll
    for (int f = 0; f < 4; ++f)  { wxf[f] = *(const bf16x8*)(w0p + f*512);     pin(wxf[f]); }
    bf16x8 wh[16];
#pragma unroll
    for (int f = 0; f < 16; ++f) { wh[f] = *(const bf16x8*)(w0p + (4+f)*512); pin(wh[f]); }

    float cA[4] = {0.f,0.f,0.f,0.f}, cB[4] = {0.f,0.f,0.f,0.f};
    float bv[4];
#pragma unroll
    for (int gt = 0; gt < 4; ++gt) bv[gt] = bias[gt*128 + ut*16 + lrow];

    const float* xrA = x + (size_t)(bbase + lrow)      * (T_SEQ*D_IN) + quad*8;
    const float* xrB = x + (size_t)(bbase + 16 + lrow) * (T_SEQ*D_IN) + quad*8;
    const int jc = (ut*16 + lrow) >> 3, jl = (ut*16 + lrow) & 7;

    // store mapping: waves 0..3 -> tile A, waves 4..7 -> tile B (proven R3)
    const int scc = (tid >> 6) & 3;      // cc 0..3 within tile
    const int sl  = tid & 63;
    const int sq2 = sl >> 4, sb = sl & 15;
    const int schunk = (scc*4 + sq2) ^ sb;
    const int stile = (tid < 256) ? (2*blk) : (2*blk + 1);
    unsigned short* sdst = h0seq + (size_t)stile*(T_SEQ*2048) + scc*512 + sl*8;
    const unsigned short* ssrc = (tid < 256) ? hA : hB;

#define L0_LDH(hrd_, ks_) (*(const bf16x8*)&(hrd_)[lrow*128 + ((((ks_)*4 + quad) ^ lrow)*8)])
#define L0_KS(accX, ah_, ks_) { \
        MFMA(accX[0], ah_, wh[(ks_)*4+0]); \
        MFMA(accX[1], ah_, wh[(ks_)*4+1]); \
        MFMA(accX[2], ah_, wh[(ks_)*4+2]); \
        MFMA(accX[3], ah_, wh[(ks_)*4+3]); }

// Full segment: compute accX(t) for tile X (reads hXrd, x regs) interleaved
// with elem of tile Y (consumes accY -> writes hYwr). NO guards.
#define L0_SEG(accX, hXrd, xlo, xhi, accY, csY, hYwr) { \
        bf16x8 f0_ = L0_LDH(hXrd, 0), f1_ = L0_LDH(hXrd, 1); \
        bf16x8 f2_ = L0_LDH(hXrd, 2), f3_ = L0_LDH(hXrd, 3); \
        u32x4 ux_; \
        ux_[0] = pkbf2((xlo).x, (xlo).y); ux_[1] = pkbf2((xlo).z, (xlo).w); \
        ux_[2] = pkbf2((xhi).x, (xhi).y); ux_[3] = pkbf2((xhi).z, (xhi).w); \
        bf16x8 ax_ = __builtin_bit_cast(bf16x8, ux_); \
        { f32x4 s_ = {bv[0],bv[0],bv[0],bv[0]}; accX[0] = s_; } \
        { f32x4 s_ = {bv[1],bv[1],bv[1],bv[1]}; accX[1] = s_; } \
        { f32x4 s_ = {bv[2],bv[2],bv[2],bv[2]}; accX[2] = s_; } \
        { f32x4 s_ = {bv[3],bv[3],bv[3],bv[3]}; accX[3] = s_; } \
        MFMA(accX[0], ax_, wxf[0]); MFMA(accX[1], ax_, wxf[1]); \
        MFMA(accX[2], ax_, wxf[2]); MFMA(accX[3], ax_, wxf[3]); \
        float e0_, e1_; \
        L0_KS(accX, f0_, 0); ELEMV(accY, csY, 0, e0_); \
        L0_KS(accX, f1_, 1); ELEMV(accY, csY, 1, e1_); WRPAIR(hYwr, 0, e0_, e1_); \
        L0_KS(accX, f2_, 2); ELEMV(accY, csY, 2, e0_); \
        L0_KS(accX, f3_, 3); ELEMV(accY, csY, 3, e1_); WRPAIR(hYwr, 2, e0_, e1_); }

    // preload x(t=0) for both tiles
    float4 loA = *(const float4*)xrA;
    float4 hiA = make_float4(0.f,0.f,0.f,0.f);
    if (quad < 3) hiA = *(const float4*)(xrA+4);
    float4 loB = *(const float4*)xrB;
    float4 hiB = make_float4(0.f,0.f,0.f,0.f);
    if (quad < 3) hiB = *(const float4*)(xrB+4);

    f32x4 accA[4], accB[4];

    __syncthreads();

    // ---- peeled seg_a(0): MFMA_A(0) only (hA zeros), no elem
    {
        bf16x8 f0_ = L0_LDH(hA, 0), f1_ = L0_LDH(hA, 1);
        bf16x8 f2_ = L0_LDH(hA, 2), f3_ = L0_LDH(hA, 3);
        u32x4 ux_;
        ux_[0] = pkbf2(loA.x, loA.y); ux_[1] = pkbf2(loA.z, loA.w);
        ux_[2] = pkbf2(hiA.x, hiA.y); ux_[3] = pkbf2(hiA.z, hiA.w);
        bf16x8 ax_ = __builtin_bit_cast(bf16x8, ux_);
#pragma unroll
        for (int gt = 0; gt < 4; ++gt) { f32x4 s_ = {bv[gt],bv[gt],bv[gt],bv[gt]}; accA[gt] = s_; }
        MFMA(accA[0], ax_, wxf[0]); MFMA(accA[1], ax_, wxf[1]);
        MFMA(accA[2], ax_, wxf[2]); MFMA(accA[3], ax_, wxf[3]);
        L0_KS(accA, f0_, 0);
        L0_KS(accA, f1_, 1);
        L0_KS(accA, f2_, 2);
        L0_KS(accA, f3_, 3);
        // prefetch xA(1)
        const float* p = xrA + 1*D_IN;
        loA = *(const float4*)p;
        hiA = make_float4(0.f,0.f,0.f,0.f);
        if (quad < 3) hiA = *(const float4*)(p+4);
    }
    LDS_BARRIER();

#pragma unroll 1
    for (int t = 0; t < T_SEQ; ++t) {
        // ---- seg_b(t): MFMA_B(t) [hB RO] + elem_A(t) [hA WO] + store h_B(t-1)
        L0_SEG(accB, hB, loB, hiB, accA, cA, hA);
        if (t + 1 < T_SEQ) {                 // prefetch xB(t+1)
            const float* p = xrB + (t+1)*D_IN;
            loB = *(const float4*)p;
            hiB = make_float4(0.f,0.f,0.f,0.f);
            if (quad < 3) hiB = *(const float4*)(p+4);
        }
        if (t > 0 && tid >= 256) {           // store h_B(t-1) (hB RO here)
            bf16x8 hv = *(const bf16x8*)&ssrc[sb*128 + schunk*8];
            *(bf16x8*)(sdst + (size_t)(t-1)*2048) = hv;
        }
        LDS_BARRIER();
        if (t + 1 < T_SEQ) {
            // ---- seg_a(t+1): MFMA_A(t+1) [hA RO] + elem_B(t) [hB WO] + store h_A(t)
            L0_SEG(accA, hA, loA, hiA, accB, cB, hB);
            if (t + 2 < T_SEQ) {             // prefetch xA(t+2)
                const float* p = xrA + (t+2)*D_IN;
                loA = *(const float4*)p;
                hiA = make_float4(0.f,0.f,0.f,0.f);
                if (quad < 3) hiA = *(const float4*)(p+4);
            }
            if (tid < 256) {                 // store h_A(t) (hA RO here)
                bf16x8 hv = *(const bf16x8*)&ssrc[sb*128 + schunk*8];
                *(bf16x8*)(sdst + (size_t)t*2048) = hv;
            }
            LDS_BARRIER();
        }
    }

    // epilogue: store h_A(27); elem_B(27) -> hB; barrier; store h_B(27)
    if (tid < 256) {
        bf16x8 hv = *(const bf16x8*)&ssrc[sb*128 + schunk*8];
        *(bf16x8*)(sdst + (size_t)(T_SEQ-1)*2048) = hv;
    }
    {
        float e0_, e1_;
        ELEMV(accB, cB, 0, e0_); ELEMV(accB, cB, 1, e1_); WRPAIR(hB, 0, e0_, e1_);
        ELEMV(accB, cB, 2, e0_); ELEMV(accB, cB, 3, e1_); WRPAIR(hB, 2, e0_, e1_);
    }
    LDS_BARRIER();
    if (tid >= 256) {
        bf16x8 hv = *(const bf16x8*)&ssrc[sb*128 + schunk*8];
        *(bf16x8*)(sdst + (size_t)(T_SEQ-1)*2048) = hv;
    }
#undef L0_LDH
#undef L0_KS
#undef L0_SEG
}

// Layer 1 + FC + log_softmax: grid 256, peeled offset-phase, unguarded
// interleave. ALL 32 weight frags PINNED (fills the 128-reg arch half at
// (2,2); accumulators live in the acc half — proven R3-R5 config).
__global__ __attribute__((amdgpu_waves_per_eu(2, 2))) __launch_bounds__(NTHR)
void lstm_l1(
    const unsigned short* __restrict__ h0seq, const unsigned short* __restrict__ W,
    const float* __restrict__ bias, const float* __restrict__ Wfc,
    const float* __restrict__ bfc, float* __restrict__ out)
{
    __shared__ __align__(16) unsigned short hA[16*128];   // 4 KB
    __shared__ __align__(16) unsigned short hB[16*128];   // 4 KB
    __shared__ float lg[320];

    const int tid = threadIdx.x, lane = tid & 63, ut = tid >> 6;
    const int lrow = lane & 15, quad = lane >> 4;
    const int blk = blockIdx.x;
    const int bbase = blk * 32;

    for (int i = tid; i < 16*128; i += NTHR) { hA[i] = 0; hB[i] = 0; }

    const unsigned short* w1p = W + NW0E + ut*16384 + lane*8;
    bf16x8 w1a[16], w1b[16];                 // Wih1 (ks0..3), Whh1 (ks4..7)
#pragma unroll
    for (int f = 0; f < 16; ++f) { w1a[f] = *(const bf16x8*)(w1p + f*512);        pin(w1a[f]); }
#pragma unroll
    for (int f = 0; f < 16; ++f) { w1b[f] = *(const bf16x8*)(w1p + (16+f)*512);   pin(w1b[f]); }

    float cA[4] = {0.f,0.f,0.f,0.f}, cB[4] = {0.f,0.f,0.f,0.f};
    float bv1[4];
#pragma unroll
    for (int gt = 0; gt < 4; ++gt) bv1[gt] = bias[512 + gt*128 + ut*16 + lrow];

    const unsigned short* sqA = h0seq + (size_t)(2*blk)   * (T_SEQ*2048) + lane*8;
    const unsigned short* sqB = h0seq + (size_t)(2*blk+1) * (T_SEQ*2048) + lane*8;
    const int jc = (ut*16 + lrow) >> 3, jl = (ut*16 + lrow) & 7;

#define L1_LDH(hrd_, ks_) (*(const bf16x8*)&(hrd_)[lrow*128 + ((((ks_)*4 + quad) ^ lrow)*8)])
#define L1_XS(accX, ga_, cc_) { \
        MFMA(accX[0], ga_[cc_], w1a[(cc_)*4+0]); \
        MFMA(accX[1], ga_[cc_], w1a[(cc_)*4+1]); \
        MFMA(accX[2], ga_[cc_], w1a[(cc_)*4+2]); \
        MFMA(accX[3], ga_[cc_], w1a[(cc_)*4+3]); }
#define L1_HS(accX, ah_, ks_) { \
        MFMA(accX[0], ah_, w1b[(ks_)*4+0]); \
        MFMA(accX[1], ah_, w1b[(ks_)*4+1]); \
        MFMA(accX[2], ah_, w1b[(ks_)*4+2]); \
        MFMA(accX[3], ah_, w1b[(ks_)*4+3]); }

// Full segment: compute accX (XS from gaX regs, HS from hXrd) interleaved
// with elem of the other tile (accY -> hYwr). NO guards.
#define L1_SEG(accX, gaX, hXrd, accY, csY, hYwr) { \
        bf16x8 f0_ = L1_LDH(hXrd, 0), f1_ = L1_LDH(hXrd, 1); \
        bf16x8 f2_ = L1_LDH(hXrd, 2), f3_ = L1_LDH(hXrd, 3); \
        { f32x4 s_ = {bv1[0],bv1[0],bv1[0],bv1[0]}; accX[0] = s_; } \
        { f32x4 s_ = {bv1[1],bv1[1],bv1[1],bv1[1]}; accX[1] = s_; } \
        { f32x4 s_ = {bv1[2],bv1[2],bv1[2],bv1[2]}; accX[2] = s_; } \
        { f32x4 s_ = {bv1[3],bv1[3],bv1[3],bv1[3]}; accX[3] = s_; } \
        float e0_, e1_; \
        L1_XS(accX, gaX, 0); \
        L1_XS(accX, gaX, 1); ELEMV(accY, csY, 0, e0_); \
        L1_XS(accX, gaX, 2); \
        L1_XS(accX, gaX, 3); ELEMV(accY, csY, 1, e1_); WRPAIR(hYwr, 0, e0_, e1_); \
        L1_HS(accX, f0_, 0); \
        L1_HS(accX, f1_, 1); ELEMV(accY, csY, 2, e0_); \
        L1_HS(accX, f2_, 2); \
        L1_HS(accX, f3_, 3); ELEMV(accY, csY, 3, e1_); WRPAIR(hYwr, 2, e0_, e1_); }

    // preload ga(t=0) for both tiles
    bf16x8 gaA[4], gaB[4];
#pragma unroll
    for (int cc = 0; cc < 4; ++cc) gaA[cc] = *(const bf16x8*)(sqA + cc*512);
#pragma unroll
    for (int cc = 0; cc < 4; ++cc) gaB[cc] = *(const bf16x8*)(sqB + cc*512);

    f32x4 accA[4], accB[4];

    __syncthreads();

    // ---- peeled seg_a(0): MFMA_A(0) only (hA zeros), no elem
    {
        bf16x8 f0_ = L1_LDH(hA, 0), f1_ = L1_LDH(hA, 1);
        bf16x8 f2_ = L1_LDH(hA, 2), f3_ = L1_LDH(hA, 3);
#pragma unroll
        for (int gt = 0; gt < 4; ++gt) { f32x4 s_ = {bv1[gt],bv1[gt],bv1[gt],bv1[gt]}; accA[gt] = s_; }
        L1_XS(accA, gaA, 0); L1_XS(accA, gaA, 1);
        L1_XS(accA, gaA, 2); L1_XS(accA, gaA, 3);
        L1_HS(accA, f0_, 0); L1_HS(accA, f1_, 1);
        L1_HS(accA, f2_, 2); L1_HS(accA, f3_, 3);
        // prefetch gaA(1)
#pragma unroll
        for (int cc = 0; cc < 4; ++cc) gaA[cc] = *(const bf16x8*)(sqA + 1*2048 + cc*512);
    }
    LDS_BARRIER();

#pragma unroll 1
    for (int t = 0; t < T_SEQ; ++t) {
        // ---- seg_b(t): MFMA_B(t) [hB RO] + elem_A(t) [hA WO]
        L1_SEG(accB, gaB, hB, accA, cA, hA);
        if (t + 1 < T_SEQ) {                 // prefetch gaB(t+1)
#pragma unroll
            for (int cc = 0; cc < 4; ++cc) gaB[cc] = *(const bf16x8*)(sqB + (t+1)*2048 + cc*512);
        }
        LDS_BARRIER();
        if (t + 1 < T_SEQ) {
            // ---- seg_a(t+1): MFMA_A(t+1) [hA RO] + elem_B(t) [hB WO]
            L1_SEG(accA, gaA, hA, accB, cB, hB);
            if (t + 2 < T_SEQ) {             // prefetch gaA(t+2)
#pragma unroll
                for (int cc = 0; cc < 4; ++cc) gaA[cc] = *(const bf16x8*)(sqA + (t+2)*2048 + cc*512);
            }
            LDS_BARRIER();
        }
    }

    // epilogue: finish tile B's last step
    {
        float e0_, e1_;
        ELEMV(accB, cB, 0, e0_); ELEMV(accB, cB, 1, e1_); WRPAIR(hB, 0, e0_, e1_);
        ELEMV(accB, cB, 2, e0_); ELEMV(accB, cB, 3, e1_); WRPAIR(hB, 2, e0_, e1_);
    }
    __syncthreads();

    // FC + log_softmax. h1(T-1): rows 0..15 in hA, 16..31 in hB.
    if (tid < 320) {
        int c = tid >> 5, b = tid & 31;
        int bl = b & 15;
        const unsigned short* hs = (b < 16) ? hA : hB;
        float s = bfc[c];
        const float* wr = Wfc + c*H;
#pragma unroll
        for (int j8 = 0; j8 < 16; ++j8) {        // vectorized LDS read (bf16x8)
            bf16x8 hv = *(const bf16x8*)&hs[bl*128 + ((j8 ^ bl)*8)];
#pragma unroll
            for (int k = 0; k < 8; ++k)
                s = fmaf(wr[j8*8 + k], bf2f((unsigned short)hv[k]), s);
        }
        lg[c*32 + b] = s;
    }
    __syncthreads();
    if (tid < 32) {
        int b = tid;
        float m = -1e30f;
#pragma unroll
        for (int c = 0; c < 10; ++c) m = fmaxf(m, lg[c*32 + b]);
        float ssum = 0.f;
#pragma unroll
        for (int c = 0; c < 10; ++c) ssum += __expf(lg[c*32 + b] - m);
        float ls = m + __logf(ssum);
        float* op = out + (size_t)(bbase + b) * 10;
#pragma unroll
        for (int c = 0; c < 10; ++c) op[c] = lg[c*32 + b] - ls;
    }
#undef L1_LDH
#undef L1_XS
#undef L1_HS
#undef L1_SEG
}

// ================= Monolithic fallback =====================
__global__ __attribute__((amdgpu_waves_per_eu(2, 2))) __launch_bounds__(NTHR)
void lstm_mfma(
    const float* __restrict__ x, const unsigned short* __restrict__ W,
    const float* __restrict__ bias,
    const float* __restrict__ Wfc, const float* __restrict__ bfc,
    float* __restrict__ out)
{
    __shared__ __align__(16) unsigned short h0s[2][32*128];
    __shared__ __align__(16) unsigned short h1s[32*128];
    __shared__ __align__(16) unsigned short wl[8*16*512];

    const int tid  = threadIdx.x;
    const int lane = tid & 63;
    const int ut   = tid >> 6;
    const int lrow = lane & 15;
    const int quad = lane >> 4;
    const int bbase = blockIdx.x * 32;

    for (int i = tid; i < 32*128; i += NTHR) { h0s[0][i] = 0; h0s[1][i] = 0; h1s[i] = 0; }
#pragma unroll
    for (int it = 0; it < 16; ++it) {
        int i = it * (NTHR*8) + tid*8;
        int utw = i >> 13, r = i & 8191;
        *(bf16x8*)&wl[i] = *(const bf16x8*)&W[NW0E + utw*16384 + 8192 + r];
    }
    const unsigned short* w0p = W + ut*(20*512) + lane*8;
    const unsigned short* w1p = W + NW0E + ut*(32*512) + lane*8;
    bf16x8 w0x[4], w0h[16], w1h[16];
#pragma unroll
    for (int f = 0; f < 4; ++f)  w0x[f] = *(const bf16x8*)(w0p + f*512);
#pragma unroll
    for (int f = 0; f < 16; ++f) w0h[f] = *(const bf16x8*)(w0p + (4+f)*512);
#pragma unroll
    for (int f = 0; f < 16; ++f) w1h[f] = *(const bf16x8*)(w1p + f*512);

    float c0[2][4], c1[2][4];
#pragma unroll
    for (int m = 0; m < 2; ++m)
#pragma unroll
        for (int r = 0; r < 4; ++r) { c0[m][r] = 0.f; c1[m][r] = 0.f; }
    float bv0[4], bv1[4];
#pragma unroll
    for (int gt = 0; gt < 4; ++gt) {
        bv0[gt] = bias[gt*128 + ut*16 + lrow];
        bv1[gt] = bias[512 + gt*128 + ut*16 + lrow];
    }
    const float* xr0 = x + (size_t)(bbase + lrow)      * (T_SEQ*D_IN) + quad*8;
    const float* xr1 = x + (size_t)(bbase + 16 + lrow) * (T_SEQ*D_IN) + quad*8;
    const int jc = (ut*16 + lrow) >> 3;
    const int jl = (ut*16 + lrow) & 7;
    __syncthreads();

    auto step = [&](const unsigned short* __restrict__ h0rd,
                    unsigned short* __restrict__ h0wr, int t) {
        f32x4 acc[2][4];
#pragma unroll
        for (int gt = 0; gt < 4; ++gt) {
            f32x4 s = {bv0[gt], bv0[gt], bv0[gt], bv0[gt]};
            acc[0][gt] = s; acc[1][gt] = s;
        }
        {
            const float* p0 = xr0 + t*D_IN;
            const float* p1 = xr1 + t*D_IN;
            float4 lo0 = *(const float4*)p0;
            float4 lo1 = *(const float4*)p1;
            float4 hi0 = make_float4(0,0,0,0), hi1 = make_float4(0,0,0,0);
            if (quad < 3) { hi0 = *(const float4*)(p0+4); hi1 = *(const float4*)(p1+4); }
            u32x4 ua0, ua1;
            ua0[0] = pkbf2(lo0.x, lo0.y); ua0[1] = pkbf2(lo0.z, lo0.w);
            ua0[2] = pkbf2(hi0.x, hi0.y); ua0[3] = pkbf2(hi0.z, hi0.w);
            ua1[0] = pkbf2(lo1.x, lo1.y); ua1[1] = pkbf2(lo1.z, lo1.w);
            ua1[2] = pkbf2(hi1.x, hi1.y); ua1[3] = pkbf2(hi1.z, hi1.w);
            bf16x8 a0 = __builtin_bit_cast(bf16x8, ua0);
            bf16x8 a1 = __builtin_bit_cast(bf16x8, ua1);
#pragma unroll
            for (int gt = 0; gt < 4; ++gt) {
                MFMA(acc[0][gt], a0, w0x[gt]);
                MFMA(acc[1][gt], a1, w0x[gt]);
            }
        }
#pragma unroll
        for (int ks = 0; ks < 4; ++ks) {
            int cc = ks*4 + quad;
            bf16x8 a0 = *(const bf16x8*)&h0rd[lrow*128      + ((cc ^ lrow)*8)];
            bf16x8 a1 = *(const bf16x8*)&h0rd[(16+lrow)*128 + ((cc ^ lrow)*8)];
#pragma unroll
            for (int gt = 0; gt < 4; ++gt) {
                MFMA(acc[0][gt], a0, w0h[ks*4+gt]);
                MFMA(acc[1][gt], a1, w0h[ks*4+gt]);
            }
        }
#pragma unroll
        for (int m = 0; m < 2; ++m) {
#pragma unroll
            for (int r = 0; r < 4; r += 2) {
                float hv[2];
#pragma unroll
                for (int q = 0; q < 2; ++q) {
                    float ig = sigm(acc[m][0][r+q]);
                    float fg = sigm(acc[m][1][r+q]);
                    float gg = tanhf_(acc[m][2][r+q]);
                    float og = sigm(acc[m][3][r+q]);
                    float c  = fg * c0[m][r+q] + ig * gg;
                    c0[m][r+q] = c;
                    hv[q] = og * tanhf_(c);
                }
                unsigned u = pkbf2(hv[0], hv[1]);
                int b0 = m*16 + quad*4 + r;
                h0wr[b0*128     + ((jc ^ (b0&15))*8)     + jl] = (unsigned short)u;
                h0wr[(b0+1)*128 + ((jc ^ ((b0+1)&15))*8) + jl] = (unsigned short)(u >> 16);
            }
        }
        __syncthreads();
#pragma unroll
        for (int gt = 0; gt < 4; ++gt) {
            f32x4 s = {bv1[gt], bv1[gt], bv1[gt], bv1[gt]};
            acc[0][gt] = s; acc[1][gt] = s;
        }
#pragma unroll
        for (int ks = 0; ks < 4; ++ks) {
            int cc = ks*4 + quad;
            bf16x8 a0 = *(const bf16x8*)&h0wr[lrow*128      + ((cc ^ lrow)*8)];
            bf16x8 a1 = *(const bf16x8*)&h0wr[(16+lrow)*128 + ((cc ^ lrow)*8)];
#pragma unroll
            for (int gt = 0; gt < 4; ++gt) {
                MFMA(acc[0][gt], a0, w1h[ks*4+gt]);
                MFMA(acc[1][gt], a1, w1h[ks*4+gt]);
            }
        }
#pragma unroll
        for (int ks = 0; ks < 4; ++ks) {
            int cc = ks*4 + quad;
            bf16x8 a0 = *(const bf16x8*)&h1s[lrow*128      + ((cc ^ lrow)*8)];
            bf16x8 a1 = *(const bf16x8*)&h1s[(16+lrow)*128 + ((cc ^ lrow)*8)];
#pragma unroll
            for (int gt = 0; gt < 4; ++gt) {
                bf16x8 bf = *(const bf16x8*)&wl[ut*8192 + (ks*4+gt)*512 + lane*8];
                MFMA(acc[0][gt], a0, bf);
                MFMA(acc[1][gt], a1, bf);
            }
        }
        __syncthreads();
#pragma unroll
        for (int m = 0; m < 2; ++m) {
#pragma unroll
            for (int r = 0; r < 4; r += 2) {
                float hv[2];
#pragma unroll
                for (int q = 0; q < 2; ++q) {
                    float ig = sigm(acc[m][0][r+q]);
                    float fg = sigm(acc[m][1][r+q]);
                    float gg = tanhf_(acc[m][2][r+q]);
                    float og = sigm(acc[m][3][r+q]);
                    float c  = fg * c1[m][r+q] + ig * gg;
                    c1[m][r+q] = c;
                    hv[q] = og * tanhf_(c);
                }
                unsigned u = pkbf2(hv[0], hv[1]);
                int b0 = m*16 + quad*4 + r;
                h1s[b0*128     + ((jc ^ (b0&15))*8)     + jl] = (unsigned short)u;
                h1s[(b0+1)*128 + ((jc ^ ((b0+1)&15))*8) + jl] = (unsigned short)(u >> 16);
            }
        }
    };
#pragma unroll 1
    for (int t2 = 0; t2 < T_SEQ/2; ++t2) {
        step(h0s[0], h0s[1], 2*t2);
        step(h0s[1], h0s[0], 2*t2 + 1);
    }
    __syncthreads();
    float* lg = (float*)&h0s[0][0];
    if (tid < 320) {
        int c = tid >> 5, b = tid & 31;
        float s = bfc[c];
        const float* wr = Wfc + c*H;
#pragma unroll 4
        for (int j = 0; j < H; ++j)
            s = fmaf(wr[j], bf2f(h1s[b*128 + (((j>>3) ^ (b&15))*8) + (j&7)]), s);
        lg[c*32 + b] = s;
    }
    __syncthreads();
    if (tid < 32) {
        int b = tid;
        float m = -1e30f;
#pragma unroll
        for (int c = 0; c < 10; ++c) m = fmaxf(m, lg[c*32 + b]);
        float ssum = 0.f;
#pragma unroll
        for (int c = 0; c < 10; ++c) ssum += __expf(lg[c*32 + b] - m);
        float ls = m + __logf(ssum);
        float* op = out + (size_t)(bbase + b) * 10;
#pragma unroll
        for (int c = 0; c < 10; ++c) op[c] = lg[c*32 + b] - ls;
    }
}

extern "C" void kernel_launch(void* const* d_in, const int* in_sizes, int n_in,
                              void* d_out, int out_size, void* d_ws, size_t ws_size,
                              hipStream_t stream) {
    const float* x    = (const float*)d_in[0];
    const float* Wih0 = (const float*)d_in[1];
    const float* Whh0 = (const float*)d_in[2];
    const float* bih0 = (const float*)d_in[3];
    const float* bhh0 = (const float*)d_in[4];
    const float* Wih1 = (const float*)d_in[5];
    const float* Whh1 = (const float*)d_in[6];
    const float* bih1 = (const float*)d_in[7];
    const float* bhh1 = (const float*)d_in[8];
    const float* Wfc  = (const float*)d_in[9];
    const float* bfc  = (const float*)d_in[10];
    float* out = (float*)d_out;

    unsigned short* W = (unsigned short*)d_ws;
    float* bias = (float*)((char*)d_ws + BIAS_OFF_BYTES);

    const int n_prep = NW0E + NW1E + 1024;
    prep<<<(n_prep + 255) / 256, 256, 0, stream>>>(Wih0, Whh0, bih0, bhh0,
                                                   Wih1, Whh1, bih1, bhh1, W, bias);
    if (ws_size >= (size_t)NEED_WS) {
        unsigned short* h0seq = (unsigned short*)((char*)d_ws + SEQ_OFF_BYTES);
        lstm_l0<<<256, NTHR, 0, stream>>>(x, W, bias, h0seq);
        lstm_l1<<<256, NTHR, 0, stream>>>(h0seq, W, bias, Wfc, bfc, out);
    } else {
        lstm_mfma<<<256, NTHR, 0, stream>>>(x, W, bias, Wfc, bfc, out);
    }
}